// Round 6
// baseline (7314.169 us; speedup 1.0000x reference)
//
#include <hip/hip_runtime.h>

typedef unsigned short u16;
typedef unsigned int u32;
typedef __attribute__((ext_vector_type(8))) short short8v;   // 8 bf16 (4 VGPR) MFMA frag
typedef __attribute__((ext_vector_type(4))) float f32x4;     // MFMA acc
typedef __attribute__((ext_vector_type(8))) u16 ush8;
typedef __attribute__((ext_vector_type(4))) u16 ush4;

__device__ __forceinline__ u16 f2bf(float x) {               // RNE f32->bf16
  u32 u = __builtin_bit_cast(u32, x);
  return (u16)((u + 0x7FFFu + ((u >> 16) & 1u)) >> 16);
}
__device__ __forceinline__ float bf2f(u16 h) {
  u32 u = ((u32)h) << 16;
  return __builtin_bit_cast(float, u);
}
__device__ __forceinline__ float sigm(float x) { return 1.f / (1.f + expf(-x)); }

typedef const __attribute__((address_space(1))) void gv_t;
typedef __attribute__((address_space(3))) void lv_t;
__device__ __forceinline__ void gload16(const void* g, void* l) {
  __builtin_amdgcn_global_load_lds((gv_t*)g, (lv_t*)l, 16, 0, 0);
}

// --- device-coherent (IF$-level) access helpers -----------------------------
__device__ __forceinline__ u32 ldsc32(const u32* p) {
  u32 v;
  asm volatile("global_load_dword %0, %1, off sc0 sc1\n\ts_waitcnt vmcnt(0)"
               : "=v"(v) : "v"(p) : "memory");
  return v;
}
__device__ __forceinline__ void stsc32(u32* p, u32 v) {
  asm volatile("global_store_dword %0, %1, off sc0 sc1" :: "v"(p), "v"(v) : "memory");
}
__device__ __forceinline__ void stsc16(u16* p, u16 v) {
  asm volatile("global_store_short %0, %1, off sc0 sc1" :: "v"(p), "v"(v) : "memory");
}

// ---------------------------------------------------------------------------
// ConvLSTM recurrence: one WG per (b, row). Computes h for all t, stores
// split-bf16 h_vec rows [t*16+b][4096].  d = r*256 + ch*16 + col.
// ---------------------------------------------------------------------------
__global__ __launch_bounds__(256) void k_conv(int cin, int xmode,
    const float* __restrict__ xin, const float* __restrict__ cw,
    const float* __restrict__ cb, u16* __restrict__ hhi, u16* __restrict__ hlo)
{
  __shared__ float zb[32 * 18];        // cin x (16+2 pad)
  __shared__ float wb[64 * 32 * 3];
  __shared__ float bb[64];
  const int tid = threadIdx.x;
  const int b = blockIdx.x >> 4, r = blockIdx.x & 15;
  const int ch = tid >> 4, col = tid & 15;
  const int cx = cin - 16;
  for (int i = tid; i < 64 * cin * 3; i += 256) wb[i] = cw[i];
  if (tid < 64) bb[tid] = cb[tid];
  for (int i = tid; i < cin * 18; i += 256) zb[i] = 0.f;  // includes pad cols
  __syncthreads();
  float h = 0.f, c = 0.f;
  for (int t = 0; t < 128; ++t) {
    if (xmode == 0) {
      if (ch == 0) zb[col + 1] = xin[((long)b * 128 + t) * 256 + r * 16 + col];
    } else {
      zb[ch * 18 + col + 1] = xin[((long)t * 16 + b) * 4096 + r * 256 + ch * 16 + col];
    }
    zb[(cx + ch) * 18 + col + 1] = h;
    __syncthreads();
    float a0 = bb[ch], a1 = bb[16 + ch], a2 = bb[32 + ch], a3 = bb[48 + ch];
    for (int ic = 0; ic < cin; ++ic) {
      float z0 = zb[ic * 18 + col], z1 = zb[ic * 18 + col + 1], z2 = zb[ic * 18 + col + 2];
      const float* w0 = &wb[((0 * 16 + ch) * cin + ic) * 3];
      const float* w1 = &wb[((1 * 16 + ch) * cin + ic) * 3];
      const float* w2 = &wb[((2 * 16 + ch) * cin + ic) * 3];
      const float* w3 = &wb[((3 * 16 + ch) * cin + ic) * 3];
      a0 += z0 * w0[0] + z1 * w0[1] + z2 * w0[2];
      a1 += z0 * w1[0] + z1 * w1[1] + z2 * w1[2];
      a2 += z0 * w2[0] + z1 * w2[1] + z2 * w2[2];
      a3 += z0 * w3[0] + z1 * w3[1] + z2 * w3[2];
    }
    __syncthreads();
    c = sigm(a1) * c + sigm(a0) * tanhf(a2);   // i,f,g,o gate order
    h = sigm(a3) * tanhf(c);
    long idx = ((long)t * 16 + b) * 4096 + (long)r * 256 + ch * 16 + col;
    u16 hh = f2bf(h);
    hhi[idx] = hh;
    hlo[idx] = f2bf(h - bf2f(hh));
  }
}

// ---------------------------------------------------------------------------
// Transpose + split: W[4096][4096] fp32 (row k, col n) -> WT_hi/lo[n][k] bf16
// ---------------------------------------------------------------------------
__global__ __launch_bounds__(256) void k_tsplit(const float* __restrict__ W,
    u16* __restrict__ hi, u16* __restrict__ lo)
{
  __shared__ float tb[32][33];
  const int tn = blockIdx.x & 127, tk = blockIdx.x >> 7;
  const int n0 = tn * 32, k0 = tk * 32;
  const int lr = threadIdx.x >> 5, lc = threadIdx.x & 31;
  #pragma unroll
  for (int i = 0; i < 4; ++i)
    tb[lr + i * 8][lc] = W[(long)(k0 + lr + i * 8) * 4096 + n0 + lc];
  __syncthreads();
  #pragma unroll
  for (int i = 0; i < 4; ++i) {
    int n = lr + i * 8;
    float v = tb[lc][n];
    long idx = (long)(n0 + n) * 4096 + k0 + lc;
    u16 h = f2bf(v);
    hi[idx] = h;
    lo[idx] = f2bf(v - bf2f(h));
  }
}

// Elementwise split (no transpose) for wv
__global__ __launch_bounds__(256) void k_split(const float* __restrict__ W,
    u16* __restrict__ hi, u16* __restrict__ lo)
{
  long i = ((long)blockIdx.x * 256 + threadIdx.x) * 4;
  const float4 v = *(const float4*)&W[i];
  u16 h0 = f2bf(v.x), h1 = f2bf(v.y), h2 = f2bf(v.z), h3 = f2bf(v.w);
  ush4 hv = {h0, h1, h2, h3};
  ush4 lv = {f2bf(v.x - bf2f(h0)), f2bf(v.y - bf2f(h1)),
             f2bf(v.z - bf2f(h2)), f2bf(v.w - bf2f(h3))};
  *(ush4*)&hi[i] = hv;
  *(ush4*)&lo[i] = lv;
}

// ---------------------------------------------------------------------------
// Split-bf16 GEMM via global_load_lds + XOR-swizzled, DOUBLE-BUFFERED LDS.
// C[M][N] = A[M][4096] * B[N][4096]^T, A/B split hi/lo bf16. K = 4096.
// grid.x = mT * nTc + nT;  grid.y = batch (strided A/B/C).
// mode 0: fp32 C.  mode 1: split hi/lo bf16 C.
// ---------------------------------------------------------------------------
__global__ __launch_bounds__(256) void k_gemm(
    const u16* __restrict__ Ahi, const u16* __restrict__ Alo, long lda, long aBS,
    const u16* __restrict__ Bhi, const u16* __restrict__ Blo, long ldb, long bBS,
    float* __restrict__ Cf, u16* __restrict__ Chi, u16* __restrict__ Clo,
    long ldc, long cBS, int nTc, int mode)
{
  __shared__ __align__(16) u16 lds[2][16384];   // per buf: PA @0, PB @8192
  const int tid = threadIdx.x;
  const int lane = tid & 63;
  const int wv = tid >> 6;
  const int bx = blockIdx.x;
  const int nT = bx % nTc;
  const int mT = bx / nTc;
  const long aOff = (long)blockIdx.y * aBS;
  const long bOff = (long)blockIdx.y * bBS;
  const long cOff = (long)blockIdx.y * cBS;
  const long aRow0 = (long)mT * 128;
  const long bRow0 = (long)nT * 128;

  // per-lane pre-swizzled global staging source (rule #21: swz both sides)
  const int l8 = lane >> 3;             // row-within-8 AND swizzle key
  const int cslot = (lane & 7) ^ l8;    // logical chunk this lane fetches
  const int ck = (cslot & 3) * 8;
  const u16* aSrc = ((cslot < 4) ? Ahi : Alo) + aOff + (aRow0 + wv * 32 + l8) * lda + ck;
  const u16* bSrc = ((cslot < 4) ? Bhi : Blo) + bOff + (bRow0 + wv * 32 + l8) * ldb + ck;
  const int ldsAo = wv * 2048;          // wave wv stages rows wv*32..+31
  const int ldsBo = 8192 + wv * 2048;

  const int r15 = lane & 15, kq = lane >> 4;
  const int s7 = r15 & 7;
  const int oHi = (kq ^ s7) * 8;        // swizzled u16 offset of hi chunk
  const int oLo = ((4 + kq) ^ s7) * 8;  // swizzled u16 offset of lo chunk
  const int aQ = (wv >> 1) * 64;        // waveM*64
  const int bQ = (wv & 1) * 64;         // waveN*64

  f32x4 acc[4][4] = {};

#define STAGE(buf, kofs)                                                     \
  {                                                                          \
    const u16* sa = aSrc + (kofs);                                           \
    const u16* sb = bSrc + (kofs);                                           \
    u16* la = &lds[buf][ldsAo];                                              \
    u16* lb = &lds[buf][ldsBo];                                              \
    gload16(sa,            la);        gload16(sa +  8 * lda, la + 512);     \
    gload16(sa + 16 * lda, la + 1024); gload16(sa + 24 * lda, la + 1536);    \
    gload16(sb,            lb);        gload16(sb +  8 * ldb, lb + 512);     \
    gload16(sb + 16 * ldb, lb + 1024); gload16(sb + 24 * ldb, lb + 1536);    \
  }

  STAGE(0, 0)
  __syncthreads();                      // vmcnt(0) drained: buf0 ready
  int cur = 0;
  for (int k0 = 0; k0 < 4096; k0 += 32) {
    if (k0 + 32 < 4096) STAGE(cur ^ 1, k0 + 32)   // flies during MFMA phase
    const u16* L = &lds[cur][0];
    short8v bh[4], bl[4];
    #pragma unroll
    for (int j = 0; j < 4; ++j) {
      int rb = 8192 + (bQ + j * 16 + r15) * 64;
      bh[j] = *(const short8v*)&L[rb + oHi];
      bl[j] = *(const short8v*)&L[rb + oLo];
    }
    #pragma unroll
    for (int i = 0; i < 4; ++i) {
      int ra = (aQ + i * 16 + r15) * 64;
      short8v ah = *(const short8v*)&L[ra + oHi];
      short8v al = *(const short8v*)&L[ra + oLo];
      #pragma unroll
      for (int j = 0; j < 4; ++j) {
        acc[i][j] = __builtin_amdgcn_mfma_f32_16x16x32_bf16(ah, bh[j], acc[i][j], 0, 0, 0);
        acc[i][j] = __builtin_amdgcn_mfma_f32_16x16x32_bf16(ah, bl[j], acc[i][j], 0, 0, 0);
        acc[i][j] = __builtin_amdgcn_mfma_f32_16x16x32_bf16(al, bh[j], acc[i][j], 0, 0, 0);
      }
    }
    __syncthreads();   // next buf staged + all reads of cur done
    cur ^= 1;
  }
#undef STAGE
  // epilogue: D row=(lane>>4)*4+reg, col=lane&15 (measured m89 layout)
  const long row0 = aRow0 + aQ;
  const long col0 = bRow0 + bQ;
  #pragma unroll
  for (int i = 0; i < 4; ++i)
    #pragma unroll
    for (int j = 0; j < 4; ++j) {
      long rr = row0 + i * 16 + kq * 4;
      long cc = col0 + j * 16 + r15;
      #pragma unroll
      for (int g = 0; g < 4; ++g) {
        float v = acc[i][j][g];
        long idx = cOff + (rr + g) * ldc + cc;
        if (mode == 0) {
          Cf[idx] = v;
        } else {
          u16 h = f2bf(v);
          Chi[idx] = h;
          Clo[idx] = f2bf(v - bf2f(h));
        }
      }
    }
}

// Softmax over strictly-past scores -> Wx[t][b][t']; also sc-zeroes barrier flags
__global__ __launch_bounds__(256) void k_softmax(const float* __restrict__ S,
    float* __restrict__ Wx, u32* __restrict__ flags)
{
  if (blockIdx.x == 0) stsc32(&flags[threadIdx.x], 0);   // flags[0..255]
  const int wv = threadIdx.x >> 6, lane = threadIdx.x & 63;
  const int idx = blockIdx.x * 4 + wv;        // = b*128 + t
  const int b = idx >> 7, t = idx & 127;
  const float* row = &S[(long)idx * 128];
  float v0 = (lane < t) ? row[lane] * 0.015625f : -1e30f;
  float v1 = (lane + 64 < t) ? row[lane + 64] * 0.015625f : -1e30f;
  float m = fmaxf(v0, v1);
  #pragma unroll
  for (int off = 32; off; off >>= 1) m = fmaxf(m, __shfl_xor(m, off));
  float e0 = (lane < t) ? expf(v0 - m) : 0.f;
  float e1 = (lane + 64 < t) ? expf(v1 - m) : 0.f;
  float s = e0 + e1;
  #pragma unroll
  for (int off = 32; off; off >>= 1) s += __shfl_xor(s, off);
  float inv = 1.f / fmaxf(s, 1e-9f);
  float* wr = &Wx[((long)t * 16 + b) * 128];
  wr[lane] = e0 * inv;
  wr[lane + 64] = e1 * inv;
}

// ---------------------------------------------------------------------------
// Persistent phase C. grid 256 (1 block/CU by LDS), 512 thr = 8 waves.
// Wvo slice pinned in regs (cap 256 VGPR: launch_bounds(512) only).
// out ring: 128 distinct [16][4096] slots; producer sc-stores (write-through
// to IF$), consumers PLAIN cached loads (first touch per XCD -> fresh fill).
// Symmetric 1-hop flag barrier, 1 per step.
// ---------------------------------------------------------------------------
__global__ __launch_bounds__(512) void k_phaseC(
    const u16* __restrict__ Wvh, const u16* __restrict__ Wvl,
    const float* __restrict__ Wx,
    const u16* __restrict__ hoh, const u16* __restrict__ hol,
    u16* __restrict__ ring_h, u16* __restrict__ ring_l,
    float* __restrict__ fdest, int dmode, u32* __restrict__ flags)
{
  __shared__ float VO_lds[128 * 256];        // [t][b*16+col]  128 KB
  __shared__ float vo_w[8][256];
  __shared__ float pctx[2][256];
  const int tid = threadIdx.x;
  const int lane = tid & 63, wv = tid >> 6;
  const int n0 = blockIdx.x * 16;
  const int r15 = lane & 15, kq = lane >> 4;
  const long kb = (long)wv * 512 + kq * 8;   // this lane's K base

  // Wvo slice -> registers, pinned (128 VGPR; budget 256 => no spill)
  short8v Bh[16], Bl[16];
  {
    const u16* bh = Wvh + (long)(n0 + r15) * 4096 + kb;
    const u16* bl = Wvl + (long)(n0 + r15) * 4096 + kb;
    #pragma unroll
    for (int c = 0; c < 16; ++c) {
      Bh[c] = *(const short8v*)(bh + c * 32);
      Bl[c] = *(const short8v*)(bl + c * 32);
    }
    #pragma unroll
    for (int c = 0; c < 16; ++c) {
      asm volatile("" : "+v"(Bh[c]));
      asm volatile("" : "+v"(Bl[c]));
    }
  }
  const long abase = (long)r15 * 4096 + kb;  // A-frag base (row = batch r15)
  const int b8 = tid >> 4, col8 = tid & 15;  // (b, col) for tid<256

  // symmetric 1-hop barrier: everyone stores own flag, everyone polls all 256
#define GBAR(n)                                                              \
  {                                                                          \
    asm volatile("s_waitcnt vmcnt(0)" ::: "memory");                         \
    __syncthreads();                                                         \
    if (tid == 0) stsc32(&flags[blockIdx.x], (n));                           \
    if (tid < 256) {                                                         \
      while (ldsc32(&flags[tid]) < (n)) __builtin_amdgcn_s_sleep(1);         \
    }                                                                        \
    __syncthreads();                                                         \
  }

  // out_0 = tanh(ho_0) -> ring[0] (sc stores -> IF$)
  if (tid < 256) {
    float v = tanhf(bf2f(hoh[(long)b8 * 12288 + n0 + col8])
                  + bf2f(hol[(long)b8 * 12288 + n0 + col8]));
    u16 hh = f2bf(v);
    long oi = (long)b8 * 4096 + n0 + col8;            // ring slot 0
    stsc16(&ring_h[oi], hh);
    stsc16(&ring_l[oi], f2bf(v - bf2f(hh)));
    if (dmode == 0) fdest[(long)b8 * 4096 + n0 + col8] = v;
    else            fdest[(long)b8 * 128 * 4096 + n0 + col8] = v;
  }
  u32 bn = 1;
  GBAR(bn) ++bn;

#define MF(a, b) acc = __builtin_amdgcn_mfma_f32_16x16x32_bf16(a, b, acc, 0, 0, 0);

  for (int t = 0; t < 127; ++t) {
    const u16* ph = ring_h + (long)t * 65536 + abase;   // plain cached loads
    const u16* pl = ring_l + (long)t * 65536 + abase;
    f32x4 acc = {0.f, 0.f, 0.f, 0.f};
    {
      short8v xh[8], xl[8];
      #pragma unroll
      for (int c = 0; c < 8; ++c) {
        xh[c] = *(const short8v*)(ph + c * 32);
        xl[c] = *(const short8v*)(pl + c * 32);
      }
      #pragma unroll
      for (int c = 0; c < 8; ++c) { MF(xh[c], Bh[c]) MF(xh[c], Bl[c]) MF(xl[c], Bh[c]) }
    }
    {
      short8v xh[8], xl[8];
      #pragma unroll
      for (int c = 0; c < 8; ++c) {
        xh[c] = *(const short8v*)(ph + 256 + c * 32);
        xl[c] = *(const short8v*)(pl + 256 + c * 32);
      }
      #pragma unroll
      for (int c = 0; c < 8; ++c) { MF(xh[c], Bh[8 + c]) MF(xh[c], Bl[8 + c]) MF(xl[c], Bh[8 + c]) }
    }

    #pragma unroll
    for (int g = 0; g < 4; ++g)
      vo_w[wv][(kq * 4 + g) * 16 + r15] = acc[g];
    __syncthreads();
    float v = 0.f;
    if (tid < 256) {
      v = vo_w[0][tid] + vo_w[1][tid] + vo_w[2][tid] + vo_w[3][tid]
        + vo_w[4][tid] + vo_w[5][tid] + vo_w[6][tid] + vo_w[7][tid];
      VO_lds[t * 256 + tid] = v;
    }
    // partial mix over past vo (p=0: even t', p=1: odd t')
    {
      const int p = tid >> 8, id = tid & 255;
      const int b = id >> 4;
      const float* wrow = &Wx[((long)(t + 1) * 16 + b) * 128];
      float ctx = 0.f;
      for (int tp = p; tp < t; tp += 2)
        ctx += wrow[tp] * VO_lds[tp * 256 + id];
      pctx[p][id] = ctx;
    }
    __syncthreads();
    if (tid < 256) {
      const float* wrow = &Wx[((long)(t + 1) * 16 + b8) * 128];
      long hix = ((long)(t + 1) * 16 + b8) * 12288 + n0 + col8;
      float o = tanhf(bf2f(hoh[hix]) + bf2f(hol[hix])
                      + pctx[0][tid] + pctx[1][tid] + wrow[t] * v);
      u16 hh = f2bf(o);
      long oi = (long)(t + 1) * 65536 + (long)b8 * 4096 + n0 + col8;  // ring slot t+1
      stsc16(&ring_h[oi], hh);
      stsc16(&ring_l[oi], f2bf(o - bf2f(hh)));
      if (dmode == 0) fdest[((long)(t + 1) * 16 + b8) * 4096 + n0 + col8] = o;
      else            fdest[((long)b8 * 128 + (t + 1)) * 4096 + n0 + col8] = o;
    }
    if (t < 126) { GBAR(bn) ++bn; }
  }
#undef GBAR
#undef MF
}

// ---------------------------------------------------------------------------
extern "C" void kernel_launch(void* const* d_in, const int* in_sizes, int n_in,
                              void* d_out, int out_size, void* d_ws, size_t ws_size,
                              hipStream_t stream)
{
  (void)in_sizes; (void)n_in; (void)out_size;
  if (ws_size < 472383488UL) return;  // need ~451 MiB scratch
  char* ws = (char*)d_ws;
  // Stacked B^T for the fused Q|K|HO GEMM: [12288][4096] split bf16
  u16* WT_hi = (u16*)(ws + 0UL);               // 96 MB
  u16* WT_lo = (u16*)(ws + 100663296UL);       // 96 MB
  u16* WV_hi = (u16*)(ws + 33554432UL);        // reuses dead WT rows
  u16* WV_lo = (u16*)(ws + 134217728UL);
  u16* QKOh  = (u16*)(ws + 201326592UL);       // [2048][12288] hi (48 MB)
  u16* QKOl  = (u16*)(ws + 251658240UL);       // lo (48 MB)
  u16* Wvo_hi = (u16*)(ws + 301989888UL);      // 32 MB (reused per layer)
  u16* Wvo_lo = (u16*)(ws + 335544320UL);      // 32 MB
  u16* Hs_hi = (u16*)(ws + 369098752UL);       // 16 MB
  u16* Hs_lo = (u16*)(ws + 385875968UL);
  float* Sb   = (float*)(ws + 402653184UL);    // 1 MB
  float* Wmx  = (float*)(ws + 403701760UL);    // 1 MB
  u32*   flg  = (u32*)(ws + 404750336UL);      // 4 KB
  float* OUT0 = (float*)(ws + 404754432UL);    // 32 MB
  u16* ring_h = (u16*)(ws + 438308864UL);      // 16 MB: 128 x [16][4096]
  u16* ring_l = (u16*)(ws + 455086080UL);      // 16 MB
  float* dout = (float*)d_out;
  const float* x_flat = (const float*)d_in[0];

  for (int l = 0; l < 2; ++l) {
    const float* cw = (const float*)d_in[1 + l * 6];
    const float* cb = (const float*)d_in[2 + l * 6];
    const float* wq = (const float*)d_in[3 + l * 6];
    const float* wk = (const float*)d_in[4 + l * 6];
    const float* wv = (const float*)d_in[5 + l * 6];
    const float* wo = (const float*)d_in[6 + l * 6];
    const int cin = (l == 0) ? 17 : 32;

    // Phase A: ConvLSTM recurrence -> split h_vec rows
    hipLaunchKernelGGL(k_conv, dim3(256), dim3(256), 0, stream,
        cin, l, (l == 0) ? x_flat : OUT0, cw, cb, Hs_hi, Hs_lo);

    // Phase B1: stack wq^T | wk^T | wo_h^T into WT, then ONE fused GEMM
    hipLaunchKernelGGL(k_tsplit, dim3(16384), dim3(256), 0, stream,
        wq, WT_hi, WT_lo);
    hipLaunchKernelGGL(k_tsplit, dim3(16384), dim3(256), 0, stream,
        wk, WT_hi + 16777216UL, WT_lo + 16777216UL);
    hipLaunchKernelGGL(k_tsplit, dim3(16384), dim3(256), 0, stream,
        wo, WT_hi + 33554432UL, WT_lo + 33554432UL);
    hipLaunchKernelGGL(k_gemm, dim3(16 * 96, 1), dim3(256), 0, stream,
        Hs_hi, Hs_lo, 4096L, 0L, WT_hi, WT_lo, 4096L, 0L,
        (float*)nullptr, QKOh, QKOl, 12288L, 0L, 96, 1);

    // Phase B2: composite Wvo^T = (wv @ wo_c)^T
    hipLaunchKernelGGL(k_tsplit, dim3(16384), dim3(256), 0, stream,
        wo + 16777216UL, WT_hi, WT_lo);                       // wo_c^T
    hipLaunchKernelGGL(k_split, dim3(16384), dim3(256), 0, stream, wv, WV_hi, WV_lo);
    hipLaunchKernelGGL(k_gemm, dim3(32 * 32, 1), dim3(256), 0, stream,
        WT_hi, WT_lo, 4096L, 0L, WV_hi, WV_lo, 4096L, 0L,
        (float*)nullptr, Wvo_hi, Wvo_lo, 4096L, 0L, 32, 1);

    // Scores via batched MFMA GEMM: S[b][t][t'] = Q[t,b,:]·K[t',b,:]
    hipLaunchKernelGGL(k_gemm, dim3(1, 16), dim3(256), 0, stream,
        QKOh, QKOl, 196608L, 12288L, QKOh + 4096, QKOl + 4096, 196608L, 12288L,
        Sb, (u16*)nullptr, (u16*)nullptr, 128L, 16384L, 1, 0);
    hipLaunchKernelGGL(k_softmax, dim3(512), dim3(256), 0, stream, Sb, Wmx, flg);

    // Phase C: ONE persistent kernel (symmetric flag barrier per step)
    hipLaunchKernelGGL(k_phaseC, dim3(256), dim3(512), 0, stream,
        Wvo_hi, Wvo_lo, Wmx, QKOh + 8192, QKOl + 8192,
        ring_h, ring_l, (l == 0) ? OUT0 : dout, l, flg);
  }
}

// Round 7
// 6774.480 us; speedup vs baseline: 1.0797x; 1.0797x over previous
//
#include <hip/hip_runtime.h>

typedef unsigned short u16;
typedef unsigned int u32;
typedef __attribute__((ext_vector_type(8))) short short8v;   // 8 bf16 (4 VGPR) MFMA frag
typedef __attribute__((ext_vector_type(4))) float f32x4;     // MFMA acc
typedef __attribute__((ext_vector_type(8))) u16 ush8;
typedef __attribute__((ext_vector_type(4))) u16 ush4;

__device__ __forceinline__ u16 f2bf(float x) {               // RNE f32->bf16
  u32 u = __builtin_bit_cast(u32, x);
  return (u16)((u + 0x7FFFu + ((u >> 16) & 1u)) >> 16);
}
__device__ __forceinline__ float bf2f(u16 h) {
  u32 u = ((u32)h) << 16;
  return __builtin_bit_cast(float, u);
}
__device__ __forceinline__ float sigm(float x) { return 1.f / (1.f + expf(-x)); }

typedef const __attribute__((address_space(1))) void gv_t;
typedef __attribute__((address_space(3))) void lv_t;
__device__ __forceinline__ void gload16(const void* g, void* l) {
  __builtin_amdgcn_global_load_lds((gv_t*)g, (lv_t*)l, 16, 0, 0);
}

// --- device-coherent (IF$-level) access helpers -----------------------------
__device__ __forceinline__ u32 ldsc32(const u32* p) {
  u32 v;
  asm volatile("global_load_dword %0, %1, off sc0 sc1\n\ts_waitcnt vmcnt(0)"
               : "=v"(v) : "v"(p) : "memory");
  return v;
}
__device__ __forceinline__ void stsc32(u32* p, u32 v) {
  asm volatile("global_store_dword %0, %1, off sc0 sc1" :: "v"(p), "v"(v) : "memory");
}
__device__ __forceinline__ void stsc16(u16* p, u16 v) {
  asm volatile("global_store_short %0, %1, off sc0 sc1" :: "v"(p), "v"(v) : "memory");
}

// ---------------------------------------------------------------------------
// ConvLSTM recurrence: one WG per (b, row). Computes h for all t, stores
// split-bf16 h_vec rows [t*16+b][4096].  d = r*256 + ch*16 + col.
// ---------------------------------------------------------------------------
__global__ __launch_bounds__(256) void k_conv(int cin, int xmode,
    const float* __restrict__ xin, const float* __restrict__ cw,
    const float* __restrict__ cb, u16* __restrict__ hhi, u16* __restrict__ hlo)
{
  __shared__ float zb[32 * 18];        // cin x (16+2 pad)
  __shared__ float wb[64 * 32 * 3];
  __shared__ float bb[64];
  const int tid = threadIdx.x;
  const int b = blockIdx.x >> 4, r = blockIdx.x & 15;
  const int ch = tid >> 4, col = tid & 15;
  const int cx = cin - 16;
  for (int i = tid; i < 64 * cin * 3; i += 256) wb[i] = cw[i];
  if (tid < 64) bb[tid] = cb[tid];
  for (int i = tid; i < cin * 18; i += 256) zb[i] = 0.f;  // includes pad cols
  __syncthreads();
  float h = 0.f, c = 0.f;
  for (int t = 0; t < 128; ++t) {
    if (xmode == 0) {
      if (ch == 0) zb[col + 1] = xin[((long)b * 128 + t) * 256 + r * 16 + col];
    } else {
      zb[ch * 18 + col + 1] = xin[((long)t * 16 + b) * 4096 + r * 256 + ch * 16 + col];
    }
    zb[(cx + ch) * 18 + col + 1] = h;
    __syncthreads();
    float a0 = bb[ch], a1 = bb[16 + ch], a2 = bb[32 + ch], a3 = bb[48 + ch];
    for (int ic = 0; ic < cin; ++ic) {
      float z0 = zb[ic * 18 + col], z1 = zb[ic * 18 + col + 1], z2 = zb[ic * 18 + col + 2];
      const float* w0 = &wb[((0 * 16 + ch) * cin + ic) * 3];
      const float* w1 = &wb[((1 * 16 + ch) * cin + ic) * 3];
      const float* w2 = &wb[((2 * 16 + ch) * cin + ic) * 3];
      const float* w3 = &wb[((3 * 16 + ch) * cin + ic) * 3];
      a0 += z0 * w0[0] + z1 * w0[1] + z2 * w0[2];
      a1 += z0 * w1[0] + z1 * w1[1] + z2 * w1[2];
      a2 += z0 * w2[0] + z1 * w2[1] + z2 * w2[2];
      a3 += z0 * w3[0] + z1 * w3[1] + z2 * w3[2];
    }
    __syncthreads();
    c = sigm(a1) * c + sigm(a0) * tanhf(a2);   // i,f,g,o gate order
    h = sigm(a3) * tanhf(c);
    long idx = ((long)t * 16 + b) * 4096 + (long)r * 256 + ch * 16 + col;
    u16 hh = f2bf(h);
    hhi[idx] = hh;
    hlo[idx] = f2bf(h - bf2f(hh));
  }
}

// ---------------------------------------------------------------------------
// Transpose + split: W[4096][4096] fp32 (row k, col n) -> WT_hi/lo[n][k] bf16
// ---------------------------------------------------------------------------
__global__ __launch_bounds__(256) void k_tsplit(const float* __restrict__ W,
    u16* __restrict__ hi, u16* __restrict__ lo)
{
  __shared__ float tb[32][33];
  const int tn = blockIdx.x & 127, tk = blockIdx.x >> 7;
  const int n0 = tn * 32, k0 = tk * 32;
  const int lr = threadIdx.x >> 5, lc = threadIdx.x & 31;
  #pragma unroll
  for (int i = 0; i < 4; ++i)
    tb[lr + i * 8][lc] = W[(long)(k0 + lr + i * 8) * 4096 + n0 + lc];
  __syncthreads();
  #pragma unroll
  for (int i = 0; i < 4; ++i) {
    int n = lr + i * 8;
    float v = tb[lc][n];
    long idx = (long)(n0 + n) * 4096 + k0 + lc;
    u16 h = f2bf(v);
    hi[idx] = h;
    lo[idx] = f2bf(v - bf2f(h));
  }
}

// Elementwise split (no transpose) for wv
__global__ __launch_bounds__(256) void k_split(const float* __restrict__ W,
    u16* __restrict__ hi, u16* __restrict__ lo)
{
  long i = ((long)blockIdx.x * 256 + threadIdx.x) * 4;
  const float4 v = *(const float4*)&W[i];
  u16 h0 = f2bf(v.x), h1 = f2bf(v.y), h2 = f2bf(v.z), h3 = f2bf(v.w);
  ush4 hv = {h0, h1, h2, h3};
  ush4 lv = {f2bf(v.x - bf2f(h0)), f2bf(v.y - bf2f(h1)),
             f2bf(v.z - bf2f(h2)), f2bf(v.w - bf2f(h3))};
  *(ush4*)&hi[i] = hv;
  *(ush4*)&lo[i] = lv;
}

// ---------------------------------------------------------------------------
// Split-bf16 GEMM via global_load_lds + XOR-swizzled, DOUBLE-BUFFERED LDS.
// C[M][N] = A[M][4096] * B[N][4096]^T, A/B split hi/lo bf16. K = 4096.
// grid.x = mT * nTc + nT;  grid.y = batch (strided A/B/C).
// mode 0: fp32 C.  mode 1: split hi/lo bf16 C.
// ---------------------------------------------------------------------------
__global__ __launch_bounds__(256) void k_gemm(
    const u16* __restrict__ Ahi, const u16* __restrict__ Alo, long lda, long aBS,
    const u16* __restrict__ Bhi, const u16* __restrict__ Blo, long ldb, long bBS,
    float* __restrict__ Cf, u16* __restrict__ Chi, u16* __restrict__ Clo,
    long ldc, long cBS, int nTc, int mode)
{
  __shared__ __align__(16) u16 lds[2][16384];   // per buf: PA @0, PB @8192
  const int tid = threadIdx.x;
  const int lane = tid & 63;
  const int wv = tid >> 6;
  const int bx = blockIdx.x;
  const int nT = bx % nTc;
  const int mT = bx / nTc;
  const long aOff = (long)blockIdx.y * aBS;
  const long bOff = (long)blockIdx.y * bBS;
  const long cOff = (long)blockIdx.y * cBS;
  const long aRow0 = (long)mT * 128;
  const long bRow0 = (long)nT * 128;

  // per-lane pre-swizzled global staging source (rule #21: swz both sides)
  const int l8 = lane >> 3;             // row-within-8 AND swizzle key
  const int cslot = (lane & 7) ^ l8;    // logical chunk this lane fetches
  const int ck = (cslot & 3) * 8;
  const u16* aSrc = ((cslot < 4) ? Ahi : Alo) + aOff + (aRow0 + wv * 32 + l8) * lda + ck;
  const u16* bSrc = ((cslot < 4) ? Bhi : Blo) + bOff + (bRow0 + wv * 32 + l8) * ldb + ck;
  const int ldsAo = wv * 2048;          // wave wv stages rows wv*32..+31
  const int ldsBo = 8192 + wv * 2048;

  const int r15 = lane & 15, kq = lane >> 4;
  const int s7 = r15 & 7;
  const int oHi = (kq ^ s7) * 8;        // swizzled u16 offset of hi chunk
  const int oLo = ((4 + kq) ^ s7) * 8;  // swizzled u16 offset of lo chunk
  const int aQ = (wv >> 1) * 64;        // waveM*64
  const int bQ = (wv & 1) * 64;         // waveN*64

  f32x4 acc[4][4] = {};

#define STAGE(buf, kofs)                                                     \
  {                                                                          \
    const u16* sa = aSrc + (kofs);                                           \
    const u16* sb = bSrc + (kofs);                                           \
    u16* la = &lds[buf][ldsAo];                                              \
    u16* lb = &lds[buf][ldsBo];                                              \
    gload16(sa,            la);        gload16(sa +  8 * lda, la + 512);     \
    gload16(sa + 16 * lda, la + 1024); gload16(sa + 24 * lda, la + 1536);    \
    gload16(sb,            lb);        gload16(sb +  8 * ldb, lb + 512);     \
    gload16(sb + 16 * ldb, lb + 1024); gload16(sb + 24 * ldb, lb + 1536);    \
  }

  STAGE(0, 0)
  __syncthreads();                      // vmcnt(0) drained: buf0 ready
  int cur = 0;
  for (int k0 = 0; k0 < 4096; k0 += 32) {
    if (k0 + 32 < 4096) STAGE(cur ^ 1, k0 + 32)   // flies during MFMA phase
    const u16* L = &lds[cur][0];
    short8v bh[4], bl[4];
    #pragma unroll
    for (int j = 0; j < 4; ++j) {
      int rb = 8192 + (bQ + j * 16 + r15) * 64;
      bh[j] = *(const short8v*)&L[rb + oHi];
      bl[j] = *(const short8v*)&L[rb + oLo];
    }
    #pragma unroll
    for (int i = 0; i < 4; ++i) {
      int ra = (aQ + i * 16 + r15) * 64;
      short8v ah = *(const short8v*)&L[ra + oHi];
      short8v al = *(const short8v*)&L[ra + oLo];
      #pragma unroll
      for (int j = 0; j < 4; ++j) {
        acc[i][j] = __builtin_amdgcn_mfma_f32_16x16x32_bf16(ah, bh[j], acc[i][j], 0, 0, 0);
        acc[i][j] = __builtin_amdgcn_mfma_f32_16x16x32_bf16(ah, bl[j], acc[i][j], 0, 0, 0);
        acc[i][j] = __builtin_amdgcn_mfma_f32_16x16x32_bf16(al, bh[j], acc[i][j], 0, 0, 0);
      }
    }
    __syncthreads();   // next buf staged + all reads of cur done
    cur ^= 1;
  }
#undef STAGE
  // epilogue: D row=(lane>>4)*4+reg, col=lane&15 (measured m89 layout)
  const long row0 = aRow0 + aQ;
  const long col0 = bRow0 + bQ;
  #pragma unroll
  for (int i = 0; i < 4; ++i)
    #pragma unroll
    for (int j = 0; j < 4; ++j) {
      long rr = row0 + i * 16 + kq * 4;
      long cc = col0 + j * 16 + r15;
      #pragma unroll
      for (int g = 0; g < 4; ++g) {
        float v = acc[i][j][g];
        long idx = cOff + (rr + g) * ldc + cc;
        if (mode == 0) {
          Cf[idx] = v;
        } else {
          u16 h = f2bf(v);
          Chi[idx] = h;
          Clo[idx] = f2bf(v - bf2f(h));
        }
      }
    }
}

// Softmax over strictly-past scores -> Wx[t][b][t']; also sc-zeroes the
// 64B-strided barrier arrival flags (block 0) and release lines (block 1).
__global__ __launch_bounds__(256) void k_softmax(const float* __restrict__ S,
    float* __restrict__ Wx, u32* __restrict__ flags, u32* __restrict__ rel)
{
  if (blockIdx.x == 0) stsc32(&flags[threadIdx.x * 16], 0);
  if (blockIdx.x == 1) stsc32(&rel[threadIdx.x * 16], 0);
  const int wv = threadIdx.x >> 6, lane = threadIdx.x & 63;
  const int idx = blockIdx.x * 4 + wv;        // = b*128 + t
  const int b = idx >> 7, t = idx & 127;
  const float* row = &S[(long)idx * 128];
  float v0 = (lane < t) ? row[lane] * 0.015625f : -1e30f;
  float v1 = (lane + 64 < t) ? row[lane + 64] * 0.015625f : -1e30f;
  float m = fmaxf(v0, v1);
  #pragma unroll
  for (int off = 32; off; off >>= 1) m = fmaxf(m, __shfl_xor(m, off));
  float e0 = (lane < t) ? expf(v0 - m) : 0.f;
  float e1 = (lane + 64 < t) ? expf(v1 - m) : 0.f;
  float s = e0 + e1;
  #pragma unroll
  for (int off = 32; off; off >>= 1) s += __shfl_xor(s, off);
  float inv = 1.f / fmaxf(s, 1e-9f);
  float* wr = &Wx[((long)t * 16 + b) * 128];
  wr[lane] = e0 * inv;
  wr[lane + 64] = e1 * inv;
}

// ---------------------------------------------------------------------------
// Persistent phase C. grid 256 (1 block/CU by LDS), 512 thr = 8 waves.
// Wvo slice pinned in regs/AGPRs. out ring: 128 slots; producers sc-store,
// consumers plain cached loads. Grid barrier = 3-hop SHARDED flag protocol:
// every line has exactly ONE poller (no hot cache lines anywhere).
// ---------------------------------------------------------------------------
__global__ __launch_bounds__(512) void k_phaseC(
    const u16* __restrict__ Wvh, const u16* __restrict__ Wvl,
    const float* __restrict__ Wx,
    const u16* __restrict__ hoh, const u16* __restrict__ hol,
    u16* __restrict__ ring_h, u16* __restrict__ ring_l,
    float* __restrict__ fdest, int dmode,
    u32* __restrict__ flags, u32* __restrict__ rel)
{
  __shared__ float VO_lds[128 * 256];        // [t][b*16+col]  128 KB
  __shared__ float vo_w[8][256];
  __shared__ float pctx[2][256];
  const int tid = threadIdx.x;
  const int lane = tid & 63, wv = tid >> 6;
  const int n0 = blockIdx.x * 16;
  const int r15 = lane & 15, kq = lane >> 4;
  const long kb = (long)wv * 512 + kq * 8;   // this lane's K base

  // Wvo slice -> registers (AGPR-resident via pin)
  short8v Bh[16], Bl[16];
  {
    const u16* bh = Wvh + (long)(n0 + r15) * 4096 + kb;
    const u16* bl = Wvl + (long)(n0 + r15) * 4096 + kb;
    #pragma unroll
    for (int c = 0; c < 16; ++c) {
      Bh[c] = *(const short8v*)(bh + c * 32);
      Bl[c] = *(const short8v*)(bl + c * 32);
    }
    #pragma unroll
    for (int c = 0; c < 16; ++c) {
      asm volatile("" : "+v"(Bh[c]));
      asm volatile("" : "+v"(Bl[c]));
    }
  }
  const long abase = (long)r15 * 4096 + kb;  // A-frag base (row = batch r15)
  const int b8 = tid >> 4, col8 = tid & 15;  // (b, col) for tid<256

  // 3-hop sharded barrier: arrive(own line) -> block0 aggregates (1 poller
  // per line) -> block0 fans out release to per-block lines (1 poller each).
#define GBAR(n)                                                              \
  {                                                                          \
    asm volatile("s_waitcnt vmcnt(0)" ::: "memory");                         \
    __syncthreads();                                                         \
    if (tid == 0) {                                                          \
      stsc32(&flags[(u32)blockIdx.x * 16], (n));                             \
      asm volatile("s_waitcnt vmcnt(0)" ::: "memory");                       \
    }                                                                        \
    if (blockIdx.x == 0) {                                                   \
      if (tid < 256) {                                                       \
        while (ldsc32(&flags[tid * 16]) < (n)) __builtin_amdgcn_s_sleep(1);  \
      }                                                                      \
      __syncthreads();                                                       \
      if (tid < 256) stsc32(&rel[tid * 16], (n));                            \
    } else if (tid == 0) {                                                   \
      while (ldsc32(&rel[(u32)blockIdx.x * 16]) < (n))                       \
        __builtin_amdgcn_s_sleep(1);                                         \
    }                                                                        \
    __syncthreads();                                                         \
  }

  // out_0 = tanh(ho_0) -> ring[0] (sc stores -> IF$)
  if (tid < 256) {
    float v = tanhf(bf2f(hoh[(long)b8 * 12288 + n0 + col8])
                  + bf2f(hol[(long)b8 * 12288 + n0 + col8]));
    u16 hh = f2bf(v);
    long oi = (long)b8 * 4096 + n0 + col8;            // ring slot 0
    stsc16(&ring_h[oi], hh);
    stsc16(&ring_l[oi], f2bf(v - bf2f(hh)));
    if (dmode == 0) fdest[(long)b8 * 4096 + n0 + col8] = v;
    else            fdest[(long)b8 * 128 * 4096 + n0 + col8] = v;
  }
  u32 bn = 1;
  GBAR(bn) ++bn;

#define MF(a, b) acc = __builtin_amdgcn_mfma_f32_16x16x32_bf16(a, b, acc, 0, 0, 0);

  for (int t = 0; t < 127; ++t) {
    const u16* ph = ring_h + (long)t * 65536 + abase;   // plain cached loads
    const u16* pl = ring_l + (long)t * 65536 + abase;
    f32x4 acc = {0.f, 0.f, 0.f, 0.f};
    {
      short8v xh[8], xl[8];
      #pragma unroll
      for (int c = 0; c < 8; ++c) {
        xh[c] = *(const short8v*)(ph + c * 32);
        xl[c] = *(const short8v*)(pl + c * 32);
      }
      #pragma unroll
      for (int c = 0; c < 8; ++c) { MF(xh[c], Bh[c]) MF(xh[c], Bl[c]) MF(xl[c], Bh[c]) }
    }
    {
      short8v xh[8], xl[8];
      #pragma unroll
      for (int c = 0; c < 8; ++c) {
        xh[c] = *(const short8v*)(ph + 256 + c * 32);
        xl[c] = *(const short8v*)(pl + 256 + c * 32);
      }
      #pragma unroll
      for (int c = 0; c < 8; ++c) { MF(xh[c], Bh[8 + c]) MF(xh[c], Bl[8 + c]) MF(xl[c], Bh[8 + c]) }
    }

    #pragma unroll
    for (int g = 0; g < 4; ++g)
      vo_w[wv][(kq * 4 + g) * 16 + r15] = acc[g];
    __syncthreads();
    float v = 0.f;
    if (tid < 256) {
      v = vo_w[0][tid] + vo_w[1][tid] + vo_w[2][tid] + vo_w[3][tid]
        + vo_w[4][tid] + vo_w[5][tid] + vo_w[6][tid] + vo_w[7][tid];
      VO_lds[t * 256 + tid] = v;
    }
    // partial mix over past vo (p=0: even t', p=1: odd t')
    {
      const int p = tid >> 8, id = tid & 255;
      const int b = id >> 4;
      const float* wrow = &Wx[((long)(t + 1) * 16 + b) * 128];
      float ctx = 0.f;
      for (int tp = p; tp < t; tp += 2)
        ctx += wrow[tp] * VO_lds[tp * 256 + id];
      pctx[p][id] = ctx;
    }
    __syncthreads();
    if (tid < 256) {
      const float* wrow = &Wx[((long)(t + 1) * 16 + b8) * 128];
      long hix = ((long)(t + 1) * 16 + b8) * 12288 + n0 + col8;
      float o = tanhf(bf2f(hoh[hix]) + bf2f(hol[hix])
                      + pctx[0][tid] + pctx[1][tid] + wrow[t] * v);
      u16 hh = f2bf(o);
      long oi = (long)(t + 1) * 65536 + (long)b8 * 4096 + n0 + col8;  // ring slot t+1
      stsc16(&ring_h[oi], hh);
      stsc16(&ring_l[oi], f2bf(o - bf2f(hh)));
      if (dmode == 0) fdest[((long)(t + 1) * 16 + b8) * 4096 + n0 + col8] = o;
      else            fdest[((long)b8 * 128 + (t + 1)) * 4096 + n0 + col8] = o;
    }
    if (t < 126) { GBAR(bn) ++bn; }
  }
#undef GBAR
#undef MF
}

// ---------------------------------------------------------------------------
extern "C" void kernel_launch(void* const* d_in, const int* in_sizes, int n_in,
                              void* d_out, int out_size, void* d_ws, size_t ws_size,
                              hipStream_t stream)
{
  (void)in_sizes; (void)n_in; (void)out_size;
  if (ws_size < 472383488UL) return;  // need ~451 MiB scratch
  char* ws = (char*)d_ws;
  // Stacked B^T for the fused Q|K|HO GEMM: [12288][4096] split bf16
  u16* WT_hi = (u16*)(ws + 0UL);               // 96 MB
  u16* WT_lo = (u16*)(ws + 100663296UL);       // 96 MB
  u16* WV_hi = (u16*)(ws + 33554432UL);        // reuses dead WT rows
  u16* WV_lo = (u16*)(ws + 134217728UL);
  u16* QKOh  = (u16*)(ws + 201326592UL);       // [2048][12288] hi (48 MB)
  u16* QKOl  = (u16*)(ws + 251658240UL);       // lo (48 MB)
  u16* Wvo_hi = (u16*)(ws + 301989888UL);      // 32 MB (reused per layer)
  u16* Wvo_lo = (u16*)(ws + 335544320UL);      // 32 MB
  u16* Hs_hi = (u16*)(ws + 369098752UL);       // 16 MB
  u16* Hs_lo = (u16*)(ws + 385875968UL);
  float* Sb   = (float*)(ws + 402653184UL);    // 1 MB
  float* Wmx  = (float*)(ws + 403701760UL);    // 1 MB
  float* OUT0 = (float*)(ws + 404754432UL);    // 32 MB
  u16* ring_h = (u16*)(ws + 438308864UL);      // 16 MB: 128 x [16][4096]
  u16* ring_l = (u16*)(ws + 455086080UL);      // 16 MB
  u32* flg    = (u32*)(ws + 471859200UL);      // 16 KB (256 x 64B lines)
  u32* rel    = (u32*)(ws + 471875584UL);      // 16 KB (256 x 64B lines)
  float* dout = (float*)d_out;
  const float* x_flat = (const float*)d_in[0];

  for (int l = 0; l < 2; ++l) {
    const float* cw = (const float*)d_in[1 + l * 6];
    const float* cb = (const float*)d_in[2 + l * 6];
    const float* wq = (const float*)d_in[3 + l * 6];
    const float* wk = (const float*)d_in[4 + l * 6];
    const float* wv = (const float*)d_in[5 + l * 6];
    const float* wo = (const float*)d_in[6 + l * 6];
    const int cin = (l == 0) ? 17 : 32;

    // Phase A: ConvLSTM recurrence -> split h_vec rows
    hipLaunchKernelGGL(k_conv, dim3(256), dim3(256), 0, stream,
        cin, l, (l == 0) ? x_flat : OUT0, cw, cb, Hs_hi, Hs_lo);

    // Phase B1: stack wq^T | wk^T | wo_h^T into WT, then ONE fused GEMM
    hipLaunchKernelGGL(k_tsplit, dim3(16384), dim3(256), 0, stream,
        wq, WT_hi, WT_lo);
    hipLaunchKernelGGL(k_tsplit, dim3(16384), dim3(256), 0, stream,
        wk, WT_hi + 16777216UL, WT_lo + 16777216UL);
    hipLaunchKernelGGL(k_tsplit, dim3(16384), dim3(256), 0, stream,
        wo, WT_hi + 33554432UL, WT_lo + 33554432UL);
    hipLaunchKernelGGL(k_gemm, dim3(16 * 96, 1), dim3(256), 0, stream,
        Hs_hi, Hs_lo, 4096L, 0L, WT_hi, WT_lo, 4096L, 0L,
        (float*)nullptr, QKOh, QKOl, 12288L, 0L, 96, 1);

    // Phase B2: composite Wvo^T = (wv @ wo_c)^T
    hipLaunchKernelGGL(k_tsplit, dim3(16384), dim3(256), 0, stream,
        wo + 16777216UL, WT_hi, WT_lo);                       // wo_c^T
    hipLaunchKernelGGL(k_split, dim3(16384), dim3(256), 0, stream, wv, WV_hi, WV_lo);
    hipLaunchKernelGGL(k_gemm, dim3(32 * 32, 1), dim3(256), 0, stream,
        WT_hi, WT_lo, 4096L, 0L, WV_hi, WV_lo, 4096L, 0L,
        (float*)nullptr, Wvo_hi, Wvo_lo, 4096L, 0L, 32, 1);

    // Scores via batched MFMA GEMM: S[b][t][t'] = Q[t,b,:]·K[t',b,:]
    hipLaunchKernelGGL(k_gemm, dim3(1, 16), dim3(256), 0, stream,
        QKOh, QKOl, 196608L, 12288L, QKOh + 4096, QKOl + 4096, 196608L, 12288L,
        Sb, (u16*)nullptr, (u16*)nullptr, 128L, 16384L, 1, 0);
    hipLaunchKernelGGL(k_softmax, dim3(512), dim3(256), 0, stream, Sb, Wmx, flg, rel);

    // Phase C: ONE persistent kernel (sharded 3-hop barrier per step)
    hipLaunchKernelGGL(k_phaseC, dim3(256), dim3(512), 0, stream,
        Wvo_hi, Wvo_lo, Wmx, QKOh + 8192, QKOl + 8192,
        ring_h, ring_l, (l == 0) ? OUT0 : dout, l, flg, rel);
  }
}

// Round 9
// 6760.989 us; speedup vs baseline: 1.0818x; 1.0020x over previous
//
#include <hip/hip_runtime.h>

typedef unsigned short u16;
typedef unsigned int u32;
typedef __attribute__((ext_vector_type(8))) short short8v;   // 8 bf16 (4 VGPR) MFMA frag
typedef __attribute__((ext_vector_type(4))) float f32x4;     // MFMA acc
typedef __attribute__((ext_vector_type(8))) u16 ush8;
typedef __attribute__((ext_vector_type(4))) u16 ush4;

__device__ __forceinline__ u16 f2bf(float x) {               // RNE f32->bf16
  u32 u = __builtin_bit_cast(u32, x);
  return (u16)((u + 0x7FFFu + ((u >> 16) & 1u)) >> 16);
}
__device__ __forceinline__ float bf2f(u16 h) {
  u32 u = ((u32)h) << 16;
  return __builtin_bit_cast(float, u);
}
__device__ __forceinline__ float sigm(float x) { return 1.f / (1.f + expf(-x)); }

typedef const __attribute__((address_space(1))) void gv_t;
typedef __attribute__((address_space(3))) void lv_t;
__device__ __forceinline__ void gload16(const void* g, void* l) {
  __builtin_amdgcn_global_load_lds((gv_t*)g, (lv_t*)l, 16, 0, 0);
}

// --- device-coherent access helpers -----------------------------------------
__device__ __forceinline__ u32 ldsc32(const u32* p) {        // bypass L1/L2
  u32 v;
  asm volatile("global_load_dword %0, %1, off sc0 sc1\n\ts_waitcnt vmcnt(0)"
               : "=v"(v) : "v"(p) : "memory");
  return v;
}
// MALL-allocating coherent store: device-scope atomic swap, NO-RETURN form
// (no vdst => no sc0 required on gfx950).
__device__ __forceinline__ void atomswap32(u32* p, u32 v) {
  asm volatile("global_atomic_swap %0, %1, off" :: "v"(p), "v"(v) : "memory");
}

// ---------------------------------------------------------------------------
// ConvLSTM recurrence: one WG per (b, row). Computes h for all t, stores
// split-bf16 h_vec rows [t*16+b][4096].  d = r*256 + ch*16 + col.
// ---------------------------------------------------------------------------
__global__ __launch_bounds__(256) void k_conv(int cin, int xmode,
    const float* __restrict__ xin, const float* __restrict__ cw,
    const float* __restrict__ cb, u16* __restrict__ hhi, u16* __restrict__ hlo)
{
  __shared__ float zb[32 * 18];        // cin x (16+2 pad)
  __shared__ float wb[64 * 32 * 3];
  __shared__ float bb[64];
  const int tid = threadIdx.x;
  const int b = blockIdx.x >> 4, r = blockIdx.x & 15;
  const int ch = tid >> 4, col = tid & 15;
  const int cx = cin - 16;
  for (int i = tid; i < 64 * cin * 3; i += 256) wb[i] = cw[i];
  if (tid < 64) bb[tid] = cb[tid];
  for (int i = tid; i < cin * 18; i += 256) zb[i] = 0.f;  // includes pad cols
  __syncthreads();
  float h = 0.f, c = 0.f;
  for (int t = 0; t < 128; ++t) {
    if (xmode == 0) {
      if (ch == 0) zb[col + 1] = xin[((long)b * 128 + t) * 256 + r * 16 + col];
    } else {
      zb[ch * 18 + col + 1] = xin[((long)t * 16 + b) * 4096 + r * 256 + ch * 16 + col];
    }
    zb[(cx + ch) * 18 + col + 1] = h;
    __syncthreads();
    float a0 = bb[ch], a1 = bb[16 + ch], a2 = bb[32 + ch], a3 = bb[48 + ch];
    for (int ic = 0; ic < cin; ++ic) {
      float z0 = zb[ic * 18 + col], z1 = zb[ic * 18 + col + 1], z2 = zb[ic * 18 + col + 2];
      const float* w0 = &wb[((0 * 16 + ch) * cin + ic) * 3];
      const float* w1 = &wb[((1 * 16 + ch) * cin + ic) * 3];
      const float* w2 = &wb[((2 * 16 + ch) * cin + ic) * 3];
      const float* w3 = &wb[((3 * 16 + ch) * cin + ic) * 3];
      a0 += z0 * w0[0] + z1 * w0[1] + z2 * w0[2];
      a1 += z0 * w1[0] + z1 * w1[1] + z2 * w1[2];
      a2 += z0 * w2[0] + z1 * w2[1] + z2 * w2[2];
      a3 += z0 * w3[0] + z1 * w3[1] + z2 * w3[2];
    }
    __syncthreads();
    c = sigm(a1) * c + sigm(a0) * tanhf(a2);   // i,f,g,o gate order
    h = sigm(a3) * tanhf(c);
    long idx = ((long)t * 16 + b) * 4096 + (long)r * 256 + ch * 16 + col;
    u16 hh = f2bf(h);
    hhi[idx] = hh;
    hlo[idx] = f2bf(h - bf2f(hh));
  }
}

// ---------------------------------------------------------------------------
// Transpose + split: W[4096][4096] fp32 (row k, col n) -> WT_hi/lo[n][k] bf16
// ---------------------------------------------------------------------------
__global__ __launch_bounds__(256) void k_tsplit(const float* __restrict__ W,
    u16* __restrict__ hi, u16* __restrict__ lo)
{
  __shared__ float tb[32][33];
  const int tn = blockIdx.x & 127, tk = blockIdx.x >> 7;
  const int n0 = tn * 32, k0 = tk * 32;
  const int lr = threadIdx.x >> 5, lc = threadIdx.x & 31;
  #pragma unroll
  for (int i = 0; i < 4; ++i)
    tb[lr + i * 8][lc] = W[(long)(k0 + lr + i * 8) * 4096 + n0 + lc];
  __syncthreads();
  #pragma unroll
  for (int i = 0; i < 4; ++i) {
    int n = lr + i * 8;
    float v = tb[lc][n];
    long idx = (long)(n0 + n) * 4096 + k0 + lc;
    u16 h = f2bf(v);
    hi[idx] = h;
    lo[idx] = f2bf(v - bf2f(h));
  }
}

// Elementwise split (no transpose) for wv
__global__ __launch_bounds__(256) void k_split(const float* __restrict__ W,
    u16* __restrict__ hi, u16* __restrict__ lo)
{
  long i = ((long)blockIdx.x * 256 + threadIdx.x) * 4;
  const float4 v = *(const float4*)&W[i];
  u16 h0 = f2bf(v.x), h1 = f2bf(v.y), h2 = f2bf(v.z), h3 = f2bf(v.w);
  ush4 hv = {h0, h1, h2, h3};
  ush4 lv = {f2bf(v.x - bf2f(h0)), f2bf(v.y - bf2f(h1)),
             f2bf(v.z - bf2f(h2)), f2bf(v.w - bf2f(h3))};
  *(ush4*)&hi[i] = hv;
  *(ush4*)&lo[i] = lv;
}

// ---------------------------------------------------------------------------
// Split-bf16 GEMM via global_load_lds + XOR-swizzled, DOUBLE-BUFFERED LDS.
// C[M][N] = A[M][4096] * B[N][4096]^T, A/B split hi/lo bf16. K = 4096.
// grid.x = mT * nTc + nT;  grid.y = batch (strided A/B/C).
// mode 0: fp32 C.  mode 1: split hi/lo bf16 C.
// ---------------------------------------------------------------------------
__global__ __launch_bounds__(256) void k_gemm(
    const u16* __restrict__ Ahi, const u16* __restrict__ Alo, long lda, long aBS,
    const u16* __restrict__ Bhi, const u16* __restrict__ Blo, long ldb, long bBS,
    float* __restrict__ Cf, u16* __restrict__ Chi, u16* __restrict__ Clo,
    long ldc, long cBS, int nTc, int mode)
{
  __shared__ __align__(16) u16 lds[2][16384];   // per buf: PA @0, PB @8192
  const int tid = threadIdx.x;
  const int lane = tid & 63;
  const int wv = tid >> 6;
  const int bx = blockIdx.x;
  const int nT = bx % nTc;
  const int mT = bx / nTc;
  const long aOff = (long)blockIdx.y * aBS;
  const long bOff = (long)blockIdx.y * bBS;
  const long cOff = (long)blockIdx.y * cBS;
  const long aRow0 = (long)mT * 128;
  const long bRow0 = (long)nT * 128;

  // per-lane pre-swizzled global staging source (rule #21: swz both sides)
  const int l8 = lane >> 3;             // row-within-8 AND swizzle key
  const int cslot = (lane & 7) ^ l8;    // logical chunk this lane fetches
  const int ck = (cslot & 3) * 8;
  const u16* aSrc = ((cslot < 4) ? Ahi : Alo) + aOff + (aRow0 + wv * 32 + l8) * lda + ck;
  const u16* bSrc = ((cslot < 4) ? Bhi : Blo) + bOff + (bRow0 + wv * 32 + l8) * ldb + ck;
  const int ldsAo = wv * 2048;          // wave wv stages rows wv*32..+31
  const int ldsBo = 8192 + wv * 2048;

  const int r15 = lane & 15, kq = lane >> 4;
  const int s7 = r15 & 7;
  const int oHi = (kq ^ s7) * 8;        // swizzled u16 offset of hi chunk
  const int oLo = ((4 + kq) ^ s7) * 8;  // swizzled u16 offset of lo chunk
  const int aQ = (wv >> 1) * 64;        // waveM*64
  const int bQ = (wv & 1) * 64;         // waveN*64

  f32x4 acc[4][4] = {};

#define STAGE(buf, kofs)                                                     \
  {                                                                          \
    const u16* sa = aSrc + (kofs);                                           \
    const u16* sb = bSrc + (kofs);                                           \
    u16* la = &lds[buf][ldsAo];                                              \
    u16* lb = &lds[buf][ldsBo];                                              \
    gload16(sa,            la);        gload16(sa +  8 * lda, la + 512);     \
    gload16(sa + 16 * lda, la + 1024); gload16(sa + 24 * lda, la + 1536);    \
    gload16(sb,            lb);        gload16(sb +  8 * ldb, lb + 512);     \
    gload16(sb + 16 * ldb, lb + 1024); gload16(sb + 24 * ldb, lb + 1536);    \
  }

  STAGE(0, 0)
  __syncthreads();                      // vmcnt(0) drained: buf0 ready
  int cur = 0;
  for (int k0 = 0; k0 < 4096; k0 += 32) {
    if (k0 + 32 < 4096) STAGE(cur ^ 1, k0 + 32)   // flies during MFMA phase
    const u16* L = &lds[cur][0];
    short8v bh[4], bl[4];
    #pragma unroll
    for (int j = 0; j < 4; ++j) {
      int rb = 8192 + (bQ + j * 16 + r15) * 64;
      bh[j] = *(const short8v*)&L[rb + oHi];
      bl[j] = *(const short8v*)&L[rb + oLo];
    }
    #pragma unroll
    for (int i = 0; i < 4; ++i) {
      int ra = (aQ + i * 16 + r15) * 64;
      short8v ah = *(const short8v*)&L[ra + oHi];
      short8v al = *(const short8v*)&L[ra + oLo];
      #pragma unroll
      for (int j = 0; j < 4; ++j) {
        acc[i][j] = __builtin_amdgcn_mfma_f32_16x16x32_bf16(ah, bh[j], acc[i][j], 0, 0, 0);
        acc[i][j] = __builtin_amdgcn_mfma_f32_16x16x32_bf16(ah, bl[j], acc[i][j], 0, 0, 0);
        acc[i][j] = __builtin_amdgcn_mfma_f32_16x16x32_bf16(al, bh[j], acc[i][j], 0, 0, 0);
      }
    }
    __syncthreads();   // next buf staged + all reads of cur done
    cur ^= 1;
  }
#undef STAGE
  // epilogue: D row=(lane>>4)*4+reg, col=lane&15 (measured m89 layout)
  const long row0 = aRow0 + aQ;
  const long col0 = bRow0 + bQ;
  #pragma unroll
  for (int i = 0; i < 4; ++i)
    #pragma unroll
    for (int j = 0; j < 4; ++j) {
      long rr = row0 + i * 16 + kq * 4;
      long cc = col0 + j * 16 + r15;
      #pragma unroll
      for (int g = 0; g < 4; ++g) {
        float v = acc[i][j][g];
        long idx = cOff + (rr + g) * ldc + cc;
        if (mode == 0) {
          Cf[idx] = v;
        } else {
          u16 h = f2bf(v);
          Chi[idx] = h;
          Clo[idx] = f2bf(v - bf2f(h));
        }
      }
    }
}

// Softmax over strictly-past scores -> Wx[t][b][t']; also zeroes the barrier
// arrival/release lines via MALL atomics.
__global__ __launch_bounds__(256) void k_softmax(const float* __restrict__ S,
    float* __restrict__ Wx, u32* __restrict__ flags, u32* __restrict__ rel)
{
  if (blockIdx.x == 0) atomswap32(&flags[threadIdx.x * 16], 0);
  if (blockIdx.x == 1) atomswap32(&rel[threadIdx.x * 16], 0);
  const int wv = threadIdx.x >> 6, lane = threadIdx.x & 63;
  const int idx = blockIdx.x * 4 + wv;        // = b*128 + t
  const int b = idx >> 7, t = idx & 127;
  const float* row = &S[(long)idx * 128];
  float v0 = (lane < t) ? row[lane] * 0.015625f : -1e30f;
  float v1 = (lane + 64 < t) ? row[lane + 64] * 0.015625f : -1e30f;
  float m = fmaxf(v0, v1);
  #pragma unroll
  for (int off = 32; off; off >>= 1) m = fmaxf(m, __shfl_xor(m, off));
  float e0 = (lane < t) ? expf(v0 - m) : 0.f;
  float e1 = (lane + 64 < t) ? expf(v1 - m) : 0.f;
  float s = e0 + e1;
  #pragma unroll
  for (int off = 32; off; off >>= 1) s += __shfl_xor(s, off);
  float inv = 1.f / fmaxf(s, 1e-9f);
  float* wr = &Wx[((long)t * 16 + b) * 128];
  wr[lane] = e0 * inv;
  wr[lane + 64] = e1 * inv;
}

// ---------------------------------------------------------------------------
// Persistent phase C. grid 256 (1 block/CU by LDS), 512 thr = 8 waves.
// Wvo slice pinned in regs/AGPRs. out ring + flags exchanged via MALL
// (device-scope no-return atomic swaps = allocating, coherent); consumers
// plain cached loads (first-touch per dispatch). Sharded 3-hop barrier.
// ---------------------------------------------------------------------------
__global__ __launch_bounds__(512) void k_phaseC(
    const u16* __restrict__ Wvh, const u16* __restrict__ Wvl,
    const float* __restrict__ Wx,
    const u16* __restrict__ hoh, const u16* __restrict__ hol,
    u16* __restrict__ ring_h, u16* __restrict__ ring_l,
    float* __restrict__ fdest, int dmode,
    u32* __restrict__ flags, u32* __restrict__ rel)
{
  __shared__ float VO_lds[128 * 256];        // [t][b*16+col]  128 KB
  __shared__ float vo_w[8][256];
  __shared__ float pctx[2][256];
  const int tid = threadIdx.x;
  const int lane = tid & 63, wv = tid >> 6;
  const int n0 = blockIdx.x * 16;
  const int r15 = lane & 15, kq = lane >> 4;
  const long kb = (long)wv * 512 + kq * 8;   // this lane's K base

  // Wvo slice -> registers (AGPR-resident via pin)
  short8v Bh[16], Bl[16];
  {
    const u16* bh = Wvh + (long)(n0 + r15) * 4096 + kb;
    const u16* bl = Wvl + (long)(n0 + r15) * 4096 + kb;
    #pragma unroll
    for (int c = 0; c < 16; ++c) {
      Bh[c] = *(const short8v*)(bh + c * 32);
      Bl[c] = *(const short8v*)(bl + c * 32);
    }
    #pragma unroll
    for (int c = 0; c < 16; ++c) {
      asm volatile("" : "+v"(Bh[c]));
      asm volatile("" : "+v"(Bl[c]));
    }
  }
  const long abase = (long)r15 * 4096 + kb;  // A-frag base (row = batch r15)
  const int b8 = tid >> 4, col8 = tid & 15;  // (b, col) for tid<256

  // 3-hop sharded barrier (atomic writes -> MALL, sc polls)
#define GBAR(n)                                                              \
  {                                                                          \
    asm volatile("s_waitcnt vmcnt(0)" ::: "memory");                         \
    __syncthreads();                                                         \
    if (tid == 0) {                                                          \
      atomswap32(&flags[(u32)blockIdx.x * 16], (n));                         \
      asm volatile("s_waitcnt vmcnt(0)" ::: "memory");                       \
    }                                                                        \
    if (blockIdx.x == 0) {                                                   \
      if (tid < 256) {                                                       \
        while (ldsc32(&flags[tid * 16]) < (n)) __builtin_amdgcn_s_sleep(1);  \
      }                                                                      \
      __syncthreads();                                                       \
      if (tid < 256) atomswap32(&rel[tid * 16], (n));                        \
    } else if (tid == 0) {                                                   \
      while (ldsc32(&rel[(u32)blockIdx.x * 16]) < (n))                       \
        __builtin_amdgcn_s_sleep(1);                                         \
    }                                                                        \
    __syncthreads();                                                         \
  }

  // pack this thread's (hi,lo) with col-partner and atomic-store to MALL
#define RING_STORE(slot, oval)                                               \
  {                                                                          \
    u16 hh_ = f2bf(oval);                                                    \
    u16 hl_ = f2bf((oval)-bf2f(hh_));                                        \
    u32 vh_ = hh_, vl_ = hl_;                                                \
    u32 ph_ = (u32)__shfl_xor((int)vh_, 1);                                  \
    u32 pl_ = (u32)__shfl_xor((int)vl_, 1);                                  \
    if (!(col8 & 1)) {                                                       \
      long oi_ = (long)(slot) * 65536 + (long)b8 * 4096 + n0 + col8;         \
      atomswap32((u32*)&ring_h[oi_], vh_ | (ph_ << 16));                     \
      atomswap32((u32*)&ring_l[oi_], vl_ | (pl_ << 16));                     \
    }                                                                        \
  }

  // out_0 = tanh(ho_0) -> ring[0]
  if (tid < 256) {
    float v = tanhf(bf2f(hoh[(long)b8 * 12288 + n0 + col8])
                  + bf2f(hol[(long)b8 * 12288 + n0 + col8]));
    RING_STORE(0, v)
    if (dmode == 0) fdest[(long)b8 * 4096 + n0 + col8] = v;
    else            fdest[(long)b8 * 128 * 4096 + n0 + col8] = v;
  }
  u32 bn = 1;
  GBAR(bn) ++bn;

#define MF(a, b) acc = __builtin_amdgcn_mfma_f32_16x16x32_bf16(a, b, acc, 0, 0, 0);

  for (int t = 0; t < 127; ++t) {
    const u16* ph = ring_h + (long)t * 65536 + abase;   // plain cached loads
    const u16* pl = ring_l + (long)t * 65536 + abase;
    f32x4 acc = {0.f, 0.f, 0.f, 0.f};
    {
      short8v xh[8], xl[8];
      #pragma unroll
      for (int c = 0; c < 8; ++c) {
        xh[c] = *(const short8v*)(ph + c * 32);
        xl[c] = *(const short8v*)(pl + c * 32);
      }
      #pragma unroll
      for (int c = 0; c < 8; ++c) { MF(xh[c], Bh[c]) MF(xh[c], Bl[c]) MF(xl[c], Bh[c]) }
    }
    {
      short8v xh[8], xl[8];
      #pragma unroll
      for (int c = 0; c < 8; ++c) {
        xh[c] = *(const short8v*)(ph + 256 + c * 32);
        xl[c] = *(const short8v*)(pl + 256 + c * 32);
      }
      #pragma unroll
      for (int c = 0; c < 8; ++c) { MF(xh[c], Bh[8 + c]) MF(xh[c], Bl[8 + c]) MF(xl[c], Bh[8 + c]) }
    }

    #pragma unroll
    for (int g = 0; g < 4; ++g)
      vo_w[wv][(kq * 4 + g) * 16 + r15] = acc[g];
    __syncthreads();
    float v = 0.f;
    if (tid < 256) {
      v = vo_w[0][tid] + vo_w[1][tid] + vo_w[2][tid] + vo_w[3][tid]
        + vo_w[4][tid] + vo_w[5][tid] + vo_w[6][tid] + vo_w[7][tid];
      VO_lds[t * 256 + tid] = v;
    }
    // partial mix over past vo (p=0: even t', p=1: odd t')
    {
      const int p = tid >> 8, id = tid & 255;
      const int b = id >> 4;
      const float* wrow = &Wx[((long)(t + 1) * 16 + b) * 128];
      float ctx = 0.f;
      for (int tp = p; tp < t; tp += 2)
        ctx += wrow[tp] * VO_lds[tp * 256 + id];
      pctx[p][id] = ctx;
    }
    __syncthreads();
    if (tid < 256) {
      const float* wrow = &Wx[((long)(t + 1) * 16 + b8) * 128];
      long hix = ((long)(t + 1) * 16 + b8) * 12288 + n0 + col8;
      float o = tanhf(bf2f(hoh[hix]) + bf2f(hol[hix])
                      + pctx[0][tid] + pctx[1][tid] + wrow[t] * v);
      RING_STORE(t + 1, o)
      if (dmode == 0) fdest[((long)(t + 1) * 16 + b8) * 4096 + n0 + col8] = o;
      else            fdest[((long)b8 * 128 + (t + 1)) * 4096 + n0 + col8] = o;
    }
    if (t < 126) { GBAR(bn) ++bn; }
  }
#undef GBAR
#undef RING_STORE
#undef MF
}

// ---------------------------------------------------------------------------
extern "C" void kernel_launch(void* const* d_in, const int* in_sizes, int n_in,
                              void* d_out, int out_size, void* d_ws, size_t ws_size,
                              hipStream_t stream)
{
  (void)in_sizes; (void)n_in; (void)out_size;
  if (ws_size < 472383488UL) return;  // need ~451 MiB scratch
  char* ws = (char*)d_ws;
  // Stacked B^T for the fused Q|K|HO GEMM: [12288][4096] split bf16
  u16* WT_hi = (u16*)(ws + 0UL);               // 96 MB
  u16* WT_lo = (u16*)(ws + 100663296UL);       // 96 MB
  u16* WV_hi = (u16*)(ws + 33554432UL);        // reuses dead WT rows
  u16* WV_lo = (u16*)(ws + 134217728UL);
  u16* QKOh  = (u16*)(ws + 201326592UL);       // [2048][12288] hi (48 MB)
  u16* QKOl  = (u16*)(ws + 251658240UL);       // lo (48 MB)
  u16* Wvo_hi = (u16*)(ws + 301989888UL);      // 32 MB (reused per layer)
  u16* Wvo_lo = (u16*)(ws + 335544320UL);      // 32 MB
  u16* Hs_hi = (u16*)(ws + 369098752UL);       // 16 MB
  u16* Hs_lo = (u16*)(ws + 385875968UL);
  float* Sb   = (float*)(ws + 402653184UL);    // 1 MB
  float* Wmx  = (float*)(ws + 403701760UL);    // 1 MB
  float* OUT0 = (float*)(ws + 404754432UL);    // 32 MB
  u16* ring_h = (u16*)(ws + 438308864UL);      // 16 MB: 128 x [16][4096]
  u16* ring_l = (u16*)(ws + 455086080UL);      // 16 MB
  u32* flg    = (u32*)(ws + 471859200UL);      // 16 KB (256 x 64B lines)
  u32* rel    = (u32*)(ws + 471875584UL);      // 16 KB (256 x 64B lines)
  float* dout = (float*)d_out;
  const float* x_flat = (const float*)d_in[0];

  for (int l = 0; l < 2; ++l) {
    const float* cw = (const float*)d_in[1 + l * 6];
    const float* cb = (const float*)d_in[2 + l * 6];
    const float* wq = (const float*)d_in[3 + l * 6];
    const float* wk = (const float*)d_in[4 + l * 6];
    const float* wv = (const float*)d_in[5 + l * 6];
    const float* wo = (const float*)d_in[6 + l * 6];
    const int cin = (l == 0) ? 17 : 32;

    // Phase A: ConvLSTM recurrence -> split h_vec rows
    hipLaunchKernelGGL(k_conv, dim3(256), dim3(256), 0, stream,
        cin, l, (l == 0) ? x_flat : OUT0, cw, cb, Hs_hi, Hs_lo);

    // Phase B1: stack wq^T | wk^T | wo_h^T into WT, then ONE fused GEMM
    hipLaunchKernelGGL(k_tsplit, dim3(16384), dim3(256), 0, stream,
        wq, WT_hi, WT_lo);
    hipLaunchKernelGGL(k_tsplit, dim3(16384), dim3(256), 0, stream,
        wk, WT_hi + 16777216UL, WT_lo + 16777216UL);
    hipLaunchKernelGGL(k_tsplit, dim3(16384), dim3(256), 0, stream,
        wo, WT_hi + 33554432UL, WT_lo + 33554432UL);
    hipLaunchKernelGGL(k_gemm, dim3(16 * 96, 1), dim3(256), 0, stream,
        Hs_hi, Hs_lo, 4096L, 0L, WT_hi, WT_lo, 4096L, 0L,
        (float*)nullptr, QKOh, QKOl, 12288L, 0L, 96, 1);

    // Phase B2: composite Wvo^T = (wv @ wo_c)^T
    hipLaunchKernelGGL(k_tsplit, dim3(16384), dim3(256), 0, stream,
        wo + 16777216UL, WT_hi, WT_lo);                       // wo_c^T
    hipLaunchKernelGGL(k_split, dim3(16384), dim3(256), 0, stream, wv, WV_hi, WV_lo);
    hipLaunchKernelGGL(k_gemm, dim3(32 * 32, 1), dim3(256), 0, stream,
        WT_hi, WT_lo, 4096L, 0L, WV_hi, WV_lo, 4096L, 0L,
        (float*)nullptr, Wvo_hi, Wvo_lo, 4096L, 0L, 32, 1);

    // Scores via batched MFMA GEMM: S[b][t][t'] = Q[t,b,:]·K[t',b,:]
    hipLaunchKernelGGL(k_gemm, dim3(1, 16), dim3(256), 0, stream,
        QKOh, QKOl, 196608L, 12288L, QKOh + 4096, QKOl + 4096, 196608L, 12288L,
        Sb, (u16*)nullptr, (u16*)nullptr, 128L, 16384L, 1, 0);
    hipLaunchKernelGGL(k_softmax, dim3(512), dim3(256), 0, stream, Sb, Wmx, flg, rel);

    // Phase C: ONE persistent kernel (MALL-resident ring + barrier)
    hipLaunchKernelGGL(k_phaseC, dim3(256), dim3(512), 0, stream,
        Wvo_hi, Wvo_lo, Wmx, QKOh + 8192, QKOl + 8192,
        ring_h, ring_l, (l == 0) ? OUT0 : dout, l, flg, rel);
  }
}

// Round 10
// 6749.822 us; speedup vs baseline: 1.0836x; 1.0017x over previous
//
#include <hip/hip_runtime.h>

typedef unsigned short u16;
typedef unsigned int u32;
typedef __attribute__((ext_vector_type(8))) short short8v;   // 8 bf16 (4 VGPR) MFMA frag
typedef __attribute__((ext_vector_type(4))) float f32x4;     // MFMA acc
typedef __attribute__((ext_vector_type(8))) u16 ush8;
typedef __attribute__((ext_vector_type(4))) u16 ush4;

__device__ __forceinline__ u16 f2bf(float x) {               // RNE f32->bf16
  u32 u = __builtin_bit_cast(u32, x);
  return (u16)((u + 0x7FFFu + ((u >> 16) & 1u)) >> 16);
}
__device__ __forceinline__ float bf2f(u16 h) {
  u32 u = ((u32)h) << 16;
  return __builtin_bit_cast(float, u);
}
__device__ __forceinline__ float sigm(float x) { return 1.f / (1.f + expf(-x)); }

typedef const __attribute__((address_space(1))) void gv_t;
typedef __attribute__((address_space(3))) void lv_t;
__device__ __forceinline__ void gload16(const void* g, void* l) {
  __builtin_amdgcn_global_load_lds((gv_t*)g, (lv_t*)l, 16, 0, 0);
}

// --- device-coherent access helpers -----------------------------------------
__device__ __forceinline__ u32 ldsc32(const u32* p) {        // bypass L1/L2
  u32 v;
  asm volatile("global_load_dword %0, %1, off sc0 sc1\n\ts_waitcnt vmcnt(0)"
               : "=v"(v) : "v"(p) : "memory");
  return v;
}
// MALL coherent store: device-scope atomic swap, NO-RETURN form
__device__ __forceinline__ void atomswap32(u32* p, u32 v) {
  asm volatile("global_atomic_swap %0, %1, off" :: "v"(p), "v"(v) : "memory");
}

// ---------------------------------------------------------------------------
// ConvLSTM recurrence: one WG per (b, row). Computes h for all t, stores
// split-bf16 h_vec rows [t*16+b][4096].  d = r*256 + ch*16 + col.
// ---------------------------------------------------------------------------
__global__ __launch_bounds__(256) void k_conv(int cin, int xmode,
    const float* __restrict__ xin, const float* __restrict__ cw,
    const float* __restrict__ cb, u16* __restrict__ hhi, u16* __restrict__ hlo)
{
  __shared__ float zb[32 * 18];        // cin x (16+2 pad)
  __shared__ float wb[64 * 32 * 3];
  __shared__ float bb[64];
  const int tid = threadIdx.x;
  const int b = blockIdx.x >> 4, r = blockIdx.x & 15;
  const int ch = tid >> 4, col = tid & 15;
  const int cx = cin - 16;
  for (int i = tid; i < 64 * cin * 3; i += 256) wb[i] = cw[i];
  if (tid < 64) bb[tid] = cb[tid];
  for (int i = tid; i < cin * 18; i += 256) zb[i] = 0.f;  // includes pad cols
  __syncthreads();
  float h = 0.f, c = 0.f;
  for (int t = 0; t < 128; ++t) {
    if (xmode == 0) {
      if (ch == 0) zb[col + 1] = xin[((long)b * 128 + t) * 256 + r * 16 + col];
    } else {
      zb[ch * 18 + col + 1] = xin[((long)t * 16 + b) * 4096 + r * 256 + ch * 16 + col];
    }
    zb[(cx + ch) * 18 + col + 1] = h;
    __syncthreads();
    float a0 = bb[ch], a1 = bb[16 + ch], a2 = bb[32 + ch], a3 = bb[48 + ch];
    for (int ic = 0; ic < cin; ++ic) {
      float z0 = zb[ic * 18 + col], z1 = zb[ic * 18 + col + 1], z2 = zb[ic * 18 + col + 2];
      const float* w0 = &wb[((0 * 16 + ch) * cin + ic) * 3];
      const float* w1 = &wb[((1 * 16 + ch) * cin + ic) * 3];
      const float* w2 = &wb[((2 * 16 + ch) * cin + ic) * 3];
      const float* w3 = &wb[((3 * 16 + ch) * cin + ic) * 3];
      a0 += z0 * w0[0] + z1 * w0[1] + z2 * w0[2];
      a1 += z0 * w1[0] + z1 * w1[1] + z2 * w1[2];
      a2 += z0 * w2[0] + z1 * w2[1] + z2 * w2[2];
      a3 += z0 * w3[0] + z1 * w3[1] + z2 * w3[2];
    }
    __syncthreads();
    c = sigm(a1) * c + sigm(a0) * tanhf(a2);   // i,f,g,o gate order
    h = sigm(a3) * tanhf(c);
    long idx = ((long)t * 16 + b) * 4096 + (long)r * 256 + ch * 16 + col;
    u16 hh = f2bf(h);
    hhi[idx] = hh;
    hlo[idx] = f2bf(h - bf2f(hh));
  }
}

// ---------------------------------------------------------------------------
// Transpose + split: W[4096][4096] fp32 (row k, col n) -> WT_hi/lo[n][k] bf16
// ---------------------------------------------------------------------------
__global__ __launch_bounds__(256) void k_tsplit(const float* __restrict__ W,
    u16* __restrict__ hi, u16* __restrict__ lo)
{
  __shared__ float tb[32][33];
  const int tn = blockIdx.x & 127, tk = blockIdx.x >> 7;
  const int n0 = tn * 32, k0 = tk * 32;
  const int lr = threadIdx.x >> 5, lc = threadIdx.x & 31;
  #pragma unroll
  for (int i = 0; i < 4; ++i)
    tb[lr + i * 8][lc] = W[(long)(k0 + lr + i * 8) * 4096 + n0 + lc];
  __syncthreads();
  #pragma unroll
  for (int i = 0; i < 4; ++i) {
    int n = lr + i * 8;
    float v = tb[lc][n];
    long idx = (long)(n0 + n) * 4096 + k0 + lc;
    u16 h = f2bf(v);
    hi[idx] = h;
    lo[idx] = f2bf(v - bf2f(h));
  }
}

// Elementwise split (no transpose) for wv
__global__ __launch_bounds__(256) void k_split(const float* __restrict__ W,
    u16* __restrict__ hi, u16* __restrict__ lo)
{
  long i = ((long)blockIdx.x * 256 + threadIdx.x) * 4;
  const float4 v = *(const float4*)&W[i];
  u16 h0 = f2bf(v.x), h1 = f2bf(v.y), h2 = f2bf(v.z), h3 = f2bf(v.w);
  ush4 hv = {h0, h1, h2, h3};
  ush4 lv = {f2bf(v.x - bf2f(h0)), f2bf(v.y - bf2f(h1)),
             f2bf(v.z - bf2f(h2)), f2bf(v.w - bf2f(h3))};
  *(ush4*)&hi[i] = hv;
  *(ush4*)&lo[i] = lv;
}

// ---------------------------------------------------------------------------
// OLD split-bf16 GEMM (2-phase dbuf) — kept for the batched scores GEMM.
// ---------------------------------------------------------------------------
__global__ __launch_bounds__(256) void k_gemm(
    const u16* __restrict__ Ahi, const u16* __restrict__ Alo, long lda, long aBS,
    const u16* __restrict__ Bhi, const u16* __restrict__ Blo, long ldb, long bBS,
    float* __restrict__ Cf, u16* __restrict__ Chi, u16* __restrict__ Clo,
    long ldc, long cBS, int nTc, int mode)
{
  __shared__ __align__(16) u16 lds[2][16384];   // per buf: PA @0, PB @8192
  const int tid = threadIdx.x;
  const int lane = tid & 63;
  const int wv = tid >> 6;
  const int bx = blockIdx.x;
  const int nT = bx % nTc;
  const int mT = bx / nTc;
  const long aOff = (long)blockIdx.y * aBS;
  const long bOff = (long)blockIdx.y * bBS;
  const long cOff = (long)blockIdx.y * cBS;
  const long aRow0 = (long)mT * 128;
  const long bRow0 = (long)nT * 128;

  const int l8 = lane >> 3;             // row-within-8 AND swizzle key
  const int cslot = (lane & 7) ^ l8;    // logical chunk this lane fetches
  const int ck = (cslot & 3) * 8;
  const u16* aSrc = ((cslot < 4) ? Ahi : Alo) + aOff + (aRow0 + wv * 32 + l8) * lda + ck;
  const u16* bSrc = ((cslot < 4) ? Bhi : Blo) + bOff + (bRow0 + wv * 32 + l8) * ldb + ck;
  const int ldsAo = wv * 2048;          // wave wv stages rows wv*32..+31
  const int ldsBo = 8192 + wv * 2048;

  const int r15 = lane & 15, kq = lane >> 4;
  const int s7 = r15 & 7;
  const int oHi = (kq ^ s7) * 8;        // swizzled u16 offset of hi chunk
  const int oLo = ((4 + kq) ^ s7) * 8;  // swizzled u16 offset of lo chunk
  const int aQ = (wv >> 1) * 64;        // waveM*64
  const int bQ = (wv & 1) * 64;         // waveN*64

  f32x4 acc[4][4] = {};

#define STAGE(buf, kofs)                                                     \
  {                                                                          \
    const u16* sa = aSrc + (kofs);                                           \
    const u16* sb = bSrc + (kofs);                                           \
    u16* la = &lds[buf][ldsAo];                                              \
    u16* lb = &lds[buf][ldsBo];                                              \
    gload16(sa,            la);        gload16(sa +  8 * lda, la + 512);     \
    gload16(sa + 16 * lda, la + 1024); gload16(sa + 24 * lda, la + 1536);    \
    gload16(sb,            lb);        gload16(sb +  8 * ldb, lb + 512);     \
    gload16(sb + 16 * ldb, lb + 1024); gload16(sb + 24 * ldb, lb + 1536);    \
  }

  STAGE(0, 0)
  __syncthreads();                      // vmcnt(0) drained: buf0 ready
  int cur = 0;
  for (int k0 = 0; k0 < 4096; k0 += 32) {
    if (k0 + 32 < 4096) STAGE(cur ^ 1, k0 + 32)   // flies during MFMA phase
    const u16* L = &lds[cur][0];
    short8v bh[4], bl[4];
    #pragma unroll
    for (int j = 0; j < 4; ++j) {
      int rb = 8192 + (bQ + j * 16 + r15) * 64;
      bh[j] = *(const short8v*)&L[rb + oHi];
      bl[j] = *(const short8v*)&L[rb + oLo];
    }
    #pragma unroll
    for (int i = 0; i < 4; ++i) {
      int ra = (aQ + i * 16 + r15) * 64;
      short8v ah = *(const short8v*)&L[ra + oHi];
      short8v al = *(const short8v*)&L[ra + oLo];
      #pragma unroll
      for (int j = 0; j < 4; ++j) {
        acc[i][j] = __builtin_amdgcn_mfma_f32_16x16x32_bf16(ah, bh[j], acc[i][j], 0, 0, 0);
        acc[i][j] = __builtin_amdgcn_mfma_f32_16x16x32_bf16(ah, bl[j], acc[i][j], 0, 0, 0);
        acc[i][j] = __builtin_amdgcn_mfma_f32_16x16x32_bf16(al, bh[j], acc[i][j], 0, 0, 0);
      }
    }
    __syncthreads();   // next buf staged + all reads of cur done
    cur ^= 1;
  }
#undef STAGE
  const long row0 = aRow0 + aQ;
  const long col0 = bRow0 + bQ;
  #pragma unroll
  for (int i = 0; i < 4; ++i)
    #pragma unroll
    for (int j = 0; j < 4; ++j) {
      long rr = row0 + i * 16 + kq * 4;
      long cc = col0 + j * 16 + r15;
      #pragma unroll
      for (int g = 0; g < 4; ++g) {
        float v = acc[i][j][g];
        long idx = cOff + (rr + g) * ldc + cc;
        if (mode == 0) {
          Cf[idx] = v;
        } else {
          u16 h = f2bf(v);
          Chi[idx] = h;
          Clo[idx] = f2bf(v - bf2f(h));
        }
      }
    }
}

// ---------------------------------------------------------------------------
// NEW 256^2-tile split-bf16 GEMM, counted-vmcnt deep pipeline (T1+T3+T4+T5).
// C[M][N] = A[M][4096]*B[N][4096]^T, split hi/lo in & out. 512 thr, 8 waves
// (2m x 4n), wave out 128x64. BK=32, 2 LDS bufs (128 KB), loads 2 tiles deep.
// Per K-tile: vmcnt(8) -> bar -> 24 ds_read -> lgkm(0) -> bar -> 96 MFMA
// interleaved with 8 gload_lds for tile t+2. Grid must be divisible by 8.
// ---------------------------------------------------------------------------
__global__ __launch_bounds__(512) void k_gemm256(
    const u16* __restrict__ Ahi, const u16* __restrict__ Alo,
    const u16* __restrict__ Bhi, const u16* __restrict__ Blo,
    u16* __restrict__ Chi, u16* __restrict__ Clo, long ldc, int nTc)
{
  __shared__ __align__(16) u16 lds[65536];      // 2 bufs x (A 16384 | B 16384)
  const int tid = threadIdx.x, lane = tid & 63, wv = tid >> 6;
  const int nwg = gridDim.x;
  const int bid = blockIdx.x;
  const int bid2 = (bid & 7) * (nwg >> 3) + (bid >> 3);  // XCD swizzle (T1)
  const int nT = bid2 % nTc, mT = bid2 / nTc;
  const long aRow0 = (long)mT * 256, bRow0 = (long)nT * 256;

  const int l8 = lane >> 3, cslot = (lane & 7) ^ l8, ck = (cslot & 3) * 8;
  const u16* aSrc = ((cslot < 4) ? Ahi : Alo) + (aRow0 + wv * 32 + l8) * 4096 + ck;
  const u16* bSrc = ((cslot < 4) ? Bhi : Blo) + (bRow0 + wv * 32 + l8) * 4096 + ck;
  const int laO = wv * 2048, lbO = 16384 + wv * 2048;

  const int r15 = lane & 15, kq = lane >> 4, s7 = r15 & 7;
  const int oHi = (kq ^ s7) * 8, oLo = ((4 + kq) ^ s7) * 8;
  const int wm = wv >> 2, wn = wv & 3;
  f32x4 acc[8][4] = {};

#define STG(buf, kofs, g)                                                    \
  {                                                                          \
    if ((g) < 4) gload16(aSrc + (kofs) + (g) * 8 * 4096,                     \
                         &lds[(buf) * 32768 + laO + (g) * 512]);             \
    else gload16(bSrc + (kofs) + ((g) - 4) * 8 * 4096,                       \
                 &lds[(buf) * 32768 + lbO + ((g) - 4) * 512]);               \
  }

  #pragma unroll
  for (int g = 0; g < 8; ++g) STG(0, 0, g)       // tile 0
  #pragma unroll
  for (int g = 0; g < 8; ++g) STG(1, 32, g)      // tile 1

  for (int kt = 0; kt < 128; ++kt) {
    if (kt < 127) { asm volatile("s_waitcnt vmcnt(8)" ::: "memory"); }
    else          { asm volatile("s_waitcnt vmcnt(0)" ::: "memory"); }
    __builtin_amdgcn_sched_barrier(0);
    __builtin_amdgcn_s_barrier();                // all waves' tile-kt loads done
    const int bb = (kt & 1) * 32768;
    short8v ah[8], al[8], bh[4], bl[4];
    #pragma unroll
    for (int j = 0; j < 4; ++j) {
      int rb = bb + 16384 + (wn * 64 + j * 16 + r15) * 64;
      bh[j] = *(const short8v*)&lds[rb + oHi];
      bl[j] = *(const short8v*)&lds[rb + oLo];
    }
    #pragma unroll
    for (int i = 0; i < 8; ++i) {
      int ra = bb + (wm * 128 + i * 16 + r15) * 64;
      ah[i] = *(const short8v*)&lds[ra + oHi];
      al[i] = *(const short8v*)&lds[ra + oLo];
    }
    asm volatile("s_waitcnt lgkmcnt(0)" ::: "memory");   // frags in regs
    __builtin_amdgcn_sched_barrier(0);                   // rule 18
    __builtin_amdgcn_s_barrier();                // all reads done -> buf free
    const bool stg = (kt < 126);
    const int nk = (kt + 2) * 32;
    __builtin_amdgcn_s_setprio(1);
    #pragma unroll
    for (int i = 0; i < 8; ++i) {
      if (stg) STG(kt & 1, nk, i)                // tile kt+2 into freed buf
      #pragma unroll
      for (int j = 0; j < 4; ++j) {
        acc[i][j] = __builtin_amdgcn_mfma_f32_16x16x32_bf16(ah[i], bh[j], acc[i][j], 0, 0, 0);
        acc[i][j] = __builtin_amdgcn_mfma_f32_16x16x32_bf16(ah[i], bl[j], acc[i][j], 0, 0, 0);
        acc[i][j] = __builtin_amdgcn_mfma_f32_16x16x32_bf16(al[i], bh[j], acc[i][j], 0, 0, 0);
      }
    }
    __builtin_amdgcn_s_setprio(0);
  }
#undef STG
  // epilogue: split-bf16 store
  const long row0 = aRow0 + wm * 128;
  const long col0 = bRow0 + wn * 64;
  #pragma unroll
  for (int i = 0; i < 8; ++i)
    #pragma unroll
    for (int j = 0; j < 4; ++j) {
      long rr = row0 + i * 16 + kq * 4;
      long cc = col0 + j * 16 + r15;
      #pragma unroll
      for (int g = 0; g < 4; ++g) {
        float v = acc[i][j][g];
        long idx = (rr + g) * ldc + cc;
        u16 h = f2bf(v);
        Chi[idx] = h;
        Clo[idx] = f2bf(v - bf2f(h));
      }
    }
}

// Softmax over strictly-past scores -> Wx[t][b][t']; also zeroes the barrier
// arrival/release lines via MALL atomics.
__global__ __launch_bounds__(256) void k_softmax(const float* __restrict__ S,
    float* __restrict__ Wx, u32* __restrict__ flags, u32* __restrict__ rel)
{
  if (blockIdx.x == 0) atomswap32(&flags[threadIdx.x * 16], 0);
  if (blockIdx.x == 1) atomswap32(&rel[threadIdx.x * 16], 0);
  const int wv = threadIdx.x >> 6, lane = threadIdx.x & 63;
  const int idx = blockIdx.x * 4 + wv;        // = b*128 + t
  const int b = idx >> 7, t = idx & 127;
  const float* row = &S[(long)idx * 128];
  float v0 = (lane < t) ? row[lane] * 0.015625f : -1e30f;
  float v1 = (lane + 64 < t) ? row[lane + 64] * 0.015625f : -1e30f;
  float m = fmaxf(v0, v1);
  #pragma unroll
  for (int off = 32; off; off >>= 1) m = fmaxf(m, __shfl_xor(m, off));
  float e0 = (lane < t) ? expf(v0 - m) : 0.f;
  float e1 = (lane + 64 < t) ? expf(v1 - m) : 0.f;
  float s = e0 + e1;
  #pragma unroll
  for (int off = 32; off; off >>= 1) s += __shfl_xor(s, off);
  float inv = 1.f / fmaxf(s, 1e-9f);
  float* wr = &Wx[((long)t * 16 + b) * 128];
  wr[lane] = e0 * inv;
  wr[lane + 64] = e1 * inv;
}

// ---------------------------------------------------------------------------
// Persistent phase C (unchanged from r9). grid 256, 512 thr = 8 waves.
// ---------------------------------------------------------------------------
__global__ __launch_bounds__(512) void k_phaseC(
    const u16* __restrict__ Wvh, const u16* __restrict__ Wvl,
    const float* __restrict__ Wx,
    const u16* __restrict__ hoh, const u16* __restrict__ hol,
    u16* __restrict__ ring_h, u16* __restrict__ ring_l,
    float* __restrict__ fdest, int dmode,
    u32* __restrict__ flags, u32* __restrict__ rel)
{
  __shared__ float VO_lds[128 * 256];        // [t][b*16+col]  128 KB
  __shared__ float vo_w[8][256];
  __shared__ float pctx[2][256];
  const int tid = threadIdx.x;
  const int lane = tid & 63, wv = tid >> 6;
  const int n0 = blockIdx.x * 16;
  const int r15 = lane & 15, kq = lane >> 4;
  const long kb = (long)wv * 512 + kq * 8;   // this lane's K base

  short8v Bh[16], Bl[16];
  {
    const u16* bh = Wvh + (long)(n0 + r15) * 4096 + kb;
    const u16* bl = Wvl + (long)(n0 + r15) * 4096 + kb;
    #pragma unroll
    for (int c = 0; c < 16; ++c) {
      Bh[c] = *(const short8v*)(bh + c * 32);
      Bl[c] = *(const short8v*)(bl + c * 32);
    }
    #pragma unroll
    for (int c = 0; c < 16; ++c) {
      asm volatile("" : "+v"(Bh[c]));
      asm volatile("" : "+v"(Bl[c]));
    }
  }
  const long abase = (long)r15 * 4096 + kb;  // A-frag base (row = batch r15)
  const int b8 = tid >> 4, col8 = tid & 15;  // (b, col) for tid<256

#define GBAR(n)                                                              \
  {                                                                          \
    asm volatile("s_waitcnt vmcnt(0)" ::: "memory");                         \
    __syncthreads();                                                         \
    if (tid == 0) {                                                          \
      atomswap32(&flags[(u32)blockIdx.x * 16], (n));                         \
      asm volatile("s_waitcnt vmcnt(0)" ::: "memory");                       \
    }                                                                        \
    if (blockIdx.x == 0) {                                                   \
      if (tid < 256) {                                                       \
        while (ldsc32(&flags[tid * 16]) < (n)) __builtin_amdgcn_s_sleep(1);  \
      }                                                                      \
      __syncthreads();                                                       \
      if (tid < 256) atomswap32(&rel[tid * 16], (n));                        \
    } else if (tid == 0) {                                                   \
      while (ldsc32(&rel[(u32)blockIdx.x * 16]) < (n))                       \
        __builtin_amdgcn_s_sleep(1);                                         \
    }                                                                        \
    __syncthreads();                                                         \
  }

#define RING_STORE(slot, oval)                                               \
  {                                                                          \
    u16 hh_ = f2bf(oval);                                                    \
    u16 hl_ = f2bf((oval)-bf2f(hh_));                                        \
    u32 vh_ = hh_, vl_ = hl_;                                                \
    u32 ph_ = (u32)__shfl_xor((int)vh_, 1);                                  \
    u32 pl_ = (u32)__shfl_xor((int)vl_, 1);                                  \
    if (!(col8 & 1)) {                                                       \
      long oi_ = (long)(slot) * 65536 + (long)b8 * 4096 + n0 + col8;         \
      atomswap32((u32*)&ring_h[oi_], vh_ | (ph_ << 16));                     \
      atomswap32((u32*)&ring_l[oi_], vl_ | (pl_ << 16));                     \
    }                                                                        \
  }

  if (tid < 256) {
    float v = tanhf(bf2f(hoh[(long)b8 * 12288 + n0 + col8])
                  + bf2f(hol[(long)b8 * 12288 + n0 + col8]));
    RING_STORE(0, v)
    if (dmode == 0) fdest[(long)b8 * 4096 + n0 + col8] = v;
    else            fdest[(long)b8 * 128 * 4096 + n0 + col8] = v;
  }
  u32 bn = 1;
  GBAR(bn) ++bn;

#define MF(a, b) acc = __builtin_amdgcn_mfma_f32_16x16x32_bf16(a, b, acc, 0, 0, 0);

  for (int t = 0; t < 127; ++t) {
    const u16* ph = ring_h + (long)t * 65536 + abase;   // plain cached loads
    const u16* pl = ring_l + (long)t * 65536 + abase;
    f32x4 acc = {0.f, 0.f, 0.f, 0.f};
    {
      short8v xh[8], xl[8];
      #pragma unroll
      for (int c = 0; c < 8; ++c) {
        xh[c] = *(const short8v*)(ph + c * 32);
        xl[c] = *(const short8v*)(pl + c * 32);
      }
      #pragma unroll
      for (int c = 0; c < 8; ++c) { MF(xh[c], Bh[c]) MF(xh[c], Bl[c]) MF(xl[c], Bh[c]) }
    }
    {
      short8v xh[8], xl[8];
      #pragma unroll
      for (int c = 0; c < 8; ++c) {
        xh[c] = *(const short8v*)(ph + 256 + c * 32);
        xl[c] = *(const short8v*)(pl + 256 + c * 32);
      }
      #pragma unroll
      for (int c = 0; c < 8; ++c) { MF(xh[c], Bh[8 + c]) MF(xh[c], Bl[8 + c]) MF(xl[c], Bh[8 + c]) }
    }

    #pragma unroll
    for (int g = 0; g < 4; ++g)
      vo_w[wv][(kq * 4 + g) * 16 + r15] = acc[g];
    __syncthreads();
    float v = 0.f;
    if (tid < 256) {
      v = vo_w[0][tid] + vo_w[1][tid] + vo_w[2][tid] + vo_w[3][tid]
        + vo_w[4][tid] + vo_w[5][tid] + vo_w[6][tid] + vo_w[7][tid];
      VO_lds[t * 256 + tid] = v;
    }
    {
      const int p = tid >> 8, id = tid & 255;
      const int b = id >> 4;
      const float* wrow = &Wx[((long)(t + 1) * 16 + b) * 128];
      float ctx = 0.f;
      for (int tp = p; tp < t; tp += 2)
        ctx += wrow[tp] * VO_lds[tp * 256 + id];
      pctx[p][id] = ctx;
    }
    __syncthreads();
    if (tid < 256) {
      const float* wrow = &Wx[((long)(t + 1) * 16 + b8) * 128];
      long hix = ((long)(t + 1) * 16 + b8) * 12288 + n0 + col8;
      float o = tanhf(bf2f(hoh[hix]) + bf2f(hol[hix])
                      + pctx[0][tid] + pctx[1][tid] + wrow[t] * v);
      RING_STORE(t + 1, o)
      if (dmode == 0) fdest[((long)(t + 1) * 16 + b8) * 4096 + n0 + col8] = o;
      else            fdest[((long)b8 * 128 + (t + 1)) * 4096 + n0 + col8] = o;
    }
    if (t < 126) { GBAR(bn) ++bn; }
  }
#undef GBAR
#undef RING_STORE
#undef MF
}

// ---------------------------------------------------------------------------
extern "C" void kernel_launch(void* const* d_in, const int* in_sizes, int n_in,
                              void* d_out, int out_size, void* d_ws, size_t ws_size,
                              hipStream_t stream)
{
  (void)in_sizes; (void)n_in; (void)out_size;
  if (ws_size < 472383488UL) return;  // need ~451 MiB scratch
  char* ws = (char*)d_ws;
  u16* WT_hi = (u16*)(ws + 0UL);               // 96 MB
  u16* WT_lo = (u16*)(ws + 100663296UL);       // 96 MB
  u16* WV_hi = (u16*)(ws + 33554432UL);        // reuses dead WT rows
  u16* WV_lo = (u16*)(ws + 134217728UL);
  u16* QKOh  = (u16*)(ws + 201326592UL);       // [2048][12288] hi (48 MB)
  u16* QKOl  = (u16*)(ws + 251658240UL);       // lo (48 MB)
  u16* Wvo_hi = (u16*)(ws + 301989888UL);      // 32 MB (reused per layer)
  u16* Wvo_lo = (u16*)(ws + 335544320UL);      // 32 MB
  u16* Hs_hi = (u16*)(ws + 369098752UL);       // 16 MB
  u16* Hs_lo = (u16*)(ws + 385875968UL);
  float* Sb   = (float*)(ws + 402653184UL);    // 1 MB
  float* Wmx  = (float*)(ws + 403701760UL);    // 1 MB
  float* OUT0 = (float*)(ws + 404754432UL);    // 32 MB
  u16* ring_h = (u16*)(ws + 438308864UL);      // 16 MB: 128 x [16][4096]
  u16* ring_l = (u16*)(ws + 455086080UL);      // 16 MB
  u32* flg    = (u32*)(ws + 471859200UL);      // 16 KB (256 x 64B lines)
  u32* rel    = (u32*)(ws + 471875584UL);      // 16 KB (256 x 64B lines)
  float* dout = (float*)d_out;
  const float* x_flat = (const float*)d_in[0];

  for (int l = 0; l < 2; ++l) {
    const float* cw = (const float*)d_in[1 + l * 6];
    const float* cb = (const float*)d_in[2 + l * 6];
    const float* wq = (const float*)d_in[3 + l * 6];
    const float* wk = (const float*)d_in[4 + l * 6];
    const float* wv = (const float*)d_in[5 + l * 6];
    const float* wo = (const float*)d_in[6 + l * 6];
    const int cin = (l == 0) ? 17 : 32;

    // Phase A: ConvLSTM recurrence -> split h_vec rows
    hipLaunchKernelGGL(k_conv, dim3(256), dim3(256), 0, stream,
        cin, l, (l == 0) ? x_flat : OUT0, cw, cb, Hs_hi, Hs_lo);

    // Phase B1: stack wq^T | wk^T | wo_h^T into WT, then ONE fused GEMM
    hipLaunchKernelGGL(k_tsplit, dim3(16384), dim3(256), 0, stream,
        wq, WT_hi, WT_lo);
    hipLaunchKernelGGL(k_tsplit, dim3(16384), dim3(256), 0, stream,
        wk, WT_hi + 16777216UL, WT_lo + 16777216UL);
    hipLaunchKernelGGL(k_tsplit, dim3(16384), dim3(256), 0, stream,
        wo, WT_hi + 33554432UL, WT_lo + 33554432UL);
    hipLaunchKernelGGL(k_gemm256, dim3(8 * 48), dim3(512), 0, stream,
        Hs_hi, Hs_lo, WT_hi, WT_lo, QKOh, QKOl, 12288L, 48);

    // Phase B2: composite Wvo^T = (wv @ wo_c)^T
    hipLaunchKernelGGL(k_tsplit, dim3(16384), dim3(256), 0, stream,
        wo + 16777216UL, WT_hi, WT_lo);                       // wo_c^T
    hipLaunchKernelGGL(k_split, dim3(16384), dim3(256), 0, stream, wv, WV_hi, WV_lo);
    hipLaunchKernelGGL(k_gemm256, dim3(16 * 16), dim3(512), 0, stream,
        WT_hi, WT_lo, WV_hi, WV_lo, Wvo_hi, Wvo_lo, 4096L, 16);

    // Scores via batched MFMA GEMM: S[b][t][t'] = Q[t,b,:]·K[t',b,:]
    hipLaunchKernelGGL(k_gemm, dim3(1, 16), dim3(256), 0, stream,
        QKOh, QKOl, 196608L, 12288L, QKOh + 4096, QKOl + 4096, 196608L, 12288L,
        Sb, (u16*)nullptr, (u16*)nullptr, 128L, 16384L, 1, 0);
    hipLaunchKernelGGL(k_softmax, dim3(512), dim3(256), 0, stream, Sb, Wmx, flg, rel);

    // Phase C: ONE persistent kernel (MALL-resident ring + barrier)
    hipLaunchKernelGGL(k_phaseC, dim3(256), dim3(512), 0, stream,
        Wvo_hi, Wvo_lo, Wmx, QKOh + 8192, QKOl + 8192,
        ring_h, ring_l, (l == 0) ? OUT0 : dout, l, flg, rel);
  }
}